// Round 2
// baseline (656.647 us; speedup 1.0000x reference)
//
#include <hip/hip_runtime.h>
#include <hip/hip_bf16.h>

typedef __attribute__((ext_vector_type(8))) __bf16 bf16x8;
typedef __attribute__((ext_vector_type(4))) float f32x4;
typedef unsigned short ushort_t;

#define Bdim 64
#define Tdim 32
#define Edim 512
#define Fdim 512
#define Hdim 1024
#define Vdim 10000

__device__ __forceinline__ float bf2f(ushort_t u) {
    unsigned int x = ((unsigned int)u) << 16;
    union { unsigned int i; float f; } c; c.i = x; return c.f;
}
__device__ __forceinline__ ushort_t f2bf(float f) {
    __hip_bfloat16 h = __float2bfloat16(f);
    union { __hip_bfloat16 h; ushort_t u; } c; c.h = h; return c.u;
}

__device__ __forceinline__ void gload_lds16(const void* g, void* l) {
    __builtin_amdgcn_global_load_lds(
        (const __attribute__((address_space(1))) unsigned int*)g,
        (__attribute__((address_space(3))) unsigned int*)l, 16, 0, 0);
}

// ---------------- Stage 0: f32 -> bf16 mirror of the weight matrices + h0 ----------------
// mirror layout (element offsets):
//   V_W: 0            (1,048,576)
//   S_W: 1,048,576    (1,048,576)
//   U_W: 2,097,152    (2,097,152)
//   W_W: 4,194,304    (4,194,304)
//   C_W: 8,388,608    (10,240,000)
//   h0 : 18,628,608   (65,536)      total 18,694,144 elements
__global__ void cvt_all(const float* __restrict__ vw, const float* __restrict__ sw,
                        const float* __restrict__ uw, const float* __restrict__ ww,
                        const float* __restrict__ cw, const float* __restrict__ h0,
                        ushort_t* __restrict__ mir) {
    long idx = ((long)blockIdx.x * blockDim.x + threadIdx.x) * 8;
    const float* src; long off;
    if      (idx <  1048576L) { src = vw; off = idx; }
    else if (idx <  2097152L) { src = sw; off = idx - 1048576L; }
    else if (idx <  4194304L) { src = uw; off = idx - 2097152L; }
    else if (idx <  8388608L) { src = ww; off = idx - 4194304L; }
    else if (idx < 18628608L) { src = cw; off = idx - 8388608L; }
    else if (idx < 18694144L) { src = h0; off = idx - 18628608L; }
    else return;
    float4 a = *(const float4*)(src + off);
    float4 b = *(const float4*)(src + off + 4);
    ushort_t o[8];
    o[0] = f2bf(a.x); o[1] = f2bf(a.y); o[2] = f2bf(a.z); o[3] = f2bf(a.w);
    o[4] = f2bf(b.x); o[5] = f2bf(b.y); o[6] = f2bf(b.z); o[7] = f2bf(b.w);
    *(int4*)(mir + idx) = *(const int4*)o;
}

// ---------------- Stage A: x = [img ; B_emb[captions[:, :-1]]], f32 -> bf16 ----------------
__global__ void build_x(const int* __restrict__ cap,
                        const float* __restrict__ img,
                        const float* __restrict__ emb,
                        ushort_t* __restrict__ X) {
    int idx = blockIdx.x * blockDim.x + threadIdx.x;  // one 8-elem chunk
    int row = idx >> 6;            // 0..2047  (= b*32 + t)
    int c8  = (idx & 63) << 3;     // element offset within row
    int b = row >> 5, t = row & 31;
    const float* src = (t == 0) ? (img + (size_t)b * Edim)
                                : (emb + (size_t)cap[b * Tdim + (t - 1)] * Edim);
    float4 a  = *(const float4*)(src + c8);
    float4 bb = *(const float4*)(src + c8 + 4);
    ushort_t o[8];
    o[0] = f2bf(a.x);  o[1] = f2bf(a.y);  o[2] = f2bf(a.z);  o[3] = f2bf(a.w);
    o[4] = f2bf(bb.x); o[5] = f2bf(bb.y); o[6] = f2bf(bb.z); o[7] = f2bf(bb.w);
    *(int4*)(X + (size_t)row * Edim + c8) = *(const int4*)o;
}

// ---------------- Generic GEMM: C[m][n] = sum_k A[m][k]*Bt[n][k] + bias[n] ----------------
// A: M x K bf16 (stride lda), Bt: N x K bf16 (stride ldb), bias f32.
// C: f32 (f32out=1) or bf16 (f32out=0), stride ldc. Grouped via blockIdx.z.
// M multiple of 128, K multiple of 64; N arbitrary (B-loads clamped, stores guarded).
__launch_bounds__(256)
__global__ void gemm_bt(const ushort_t* __restrict__ A, long lda, long gsA,
                        const ushort_t* __restrict__ Bm, long ldb, long gsB,
                        void* __restrict__ Cv, long ldc, long gsC,
                        const float* __restrict__ bias, long gsBias,
                        int N, int K, int f32out) {
    __shared__ ushort_t As[128 * 64];
    __shared__ ushort_t Bs[128 * 64];
    int z = blockIdx.z;
    A += (size_t)z * gsA; Bm += (size_t)z * gsB; bias += (size_t)z * gsBias;
    int tid = threadIdx.x;
    int w = tid >> 6, l = tid & 63;
    int wm = (w >> 1) * 64, wn = (w & 1) * 64;
    int m0 = blockIdx.y * 128, n0 = blockIdx.x * 128;

    int srow = tid >> 3;          // 0..31 ; +32*j covers 128 rows
    int scol = (tid & 7) << 3;    // 0..56 step 8 elements

    int lane_r = l & 15;
    int lane_k = (l >> 4) << 3;   // 0,8,16,24

    f32x4 zero = {0.f, 0.f, 0.f, 0.f};
    f32x4 acc[4][4];
#pragma unroll
    for (int i = 0; i < 4; i++)
#pragma unroll
        for (int j = 0; j < 4; j++) acc[i][j] = zero;

    for (int k0 = 0; k0 < K; k0 += 64) {
#pragma unroll
        for (int j = 0; j < 4; j++) {
            int r = srow + j * 32;
            gload_lds16(A + (size_t)(m0 + r) * lda + k0 + scol, &As[r * 64 + scol]);
        }
#pragma unroll
        for (int j = 0; j < 4; j++) {
            int r = srow + j * 32;
            int br = n0 + r; if (br > N - 1) br = N - 1;
            gload_lds16(Bm + (size_t)br * ldb + k0 + scol, &Bs[r * 64 + scol]);
        }
        __syncthreads();
#pragma unroll
        for (int kk = 0; kk < 64; kk += 32) {
            bf16x8 af[4], bfr[4];
#pragma unroll
            for (int i = 0; i < 4; i++)
                af[i] = *(const bf16x8*)&As[(wm + i * 16 + lane_r) * 64 + kk + lane_k];
#pragma unroll
            for (int j = 0; j < 4; j++)
                bfr[j] = *(const bf16x8*)&Bs[(wn + j * 16 + lane_r) * 64 + kk + lane_k];
#pragma unroll
            for (int i = 0; i < 4; i++)
#pragma unroll
                for (int j = 0; j < 4; j++)
                    acc[i][j] = __builtin_amdgcn_mfma_f32_16x16x32_bf16(af[i], bfr[j], acc[i][j], 0, 0, 0);
        }
        __syncthreads();
    }

    int row_base = m0 + wm + ((l >> 4) << 2);
    int col_base = n0 + wn + lane_r;
#pragma unroll
    for (int j = 0; j < 4; j++) {
        int col = col_base + j * 16;
        if (col < N) {
            float bv = bias[col];
#pragma unroll
            for (int i = 0; i < 4; i++) {
#pragma unroll
                for (int r = 0; r < 4; r++) {
                    int row = row_base + i * 16 + r;
                    float v = acc[i][j][r] + bv;
                    if (f32out)
                        ((float*)Cv)[(size_t)z * gsC + (size_t)row * ldc + col] = v;
                    else
                        ((ushort_t*)Cv)[(size_t)z * gsC + (size_t)row * ldc + col] = f2bf(v);
                }
            }
        }
    }
}

// ---------------- Stage E: one LSTM step ----------------
// grid = 64 blocks; block bid owns h-columns [bid*16, bid*16+16) for all 4 gates.
__launch_bounds__(256)
__global__ void lstm_step(const ushort_t* __restrict__ hprev, long lda,
                          const ushort_t* __restrict__ W,    // W_W bf16 [4][1024][1024]
                          const float* __restrict__ Wb,      // W_b f32 [4][1024]
                          const ushort_t* __restrict__ g3,   // [b][t][4][1024] bf16
                          const float* __restrict__ cin,     // [64][1024] f32
                          float* __restrict__ c_ws,          // [64][1024] f32
                          ushort_t* __restrict__ Hbuf,       // [b][t][1024] bf16
                          int t) {
    __shared__ ushort_t As[64 * 32];
    __shared__ ushort_t Bs[64 * 32];
    int bid = blockIdx.x;
    int tid = threadIdx.x;
    int w = tid >> 6, l = tid & 63;
    int lane_r = l & 15, lane_k = (l >> 4) << 3;
    int srow = tid >> 2;           // 0..63
    int scol = (tid & 3) << 3;     // 0,8,16,24

    f32x4 zero = {0.f, 0.f, 0.f, 0.f};
    f32x4 acc[4];
#pragma unroll
    for (int g = 0; g < 4; g++) acc[g] = zero;

    int gg = srow >> 4, jj = srow & 15;
    const ushort_t* wrow = W + ((size_t)(gg * Hdim + bid * 16 + jj)) * Hdim;

    for (int k0 = 0; k0 < Hdim; k0 += 32) {
        gload_lds16(hprev + (size_t)srow * lda + k0 + scol, &As[srow * 32 + scol]);
        gload_lds16(wrow + k0 + scol, &Bs[srow * 32 + scol]);
        __syncthreads();
        bf16x8 a = *(const bf16x8*)&As[(w * 16 + lane_r) * 32 + lane_k];
#pragma unroll
        for (int g = 0; g < 4; g++) {
            bf16x8 b = *(const bf16x8*)&Bs[(g * 16 + lane_r) * 32 + lane_k];
            acc[g] = __builtin_amdgcn_mfma_f32_16x16x32_bf16(a, b, acc[g], 0, 0, 0);
        }
        __syncthreads();
    }

    int hcol = bid * 16 + lane_r;
#pragma unroll
    for (int r = 0; r < 4; r++) {
        int b = w * 16 + ((l >> 4) << 2) + r;
        float zv[4];
#pragma unroll
        for (int g = 0; g < 4; g++) {
            float wb = Wb[g * Hdim + hcol];
            float gv = bf2f(g3[(((size_t)b * Tdim + t) * 4 + g) * Hdim + hcol]);
            zv[g] = acc[g][r] + wb + gv;
        }
        float i_t = 1.f / (1.f + expf(-zv[0]));
        float f_t = 1.f / (1.f + expf(-zv[1]));
        float o_t = 1.f / (1.f + expf(-zv[2]));
        float ct  = tanhf(zv[3]);
        float cn = f_t * cin[b * Hdim + hcol] + i_t * ct;
        c_ws[b * Hdim + hcol] = cn;
        Hbuf[((size_t)b * Tdim + t) * Hdim + hcol] = f2bf(o_t * cn);
    }
}

extern "C" void kernel_launch(void* const* d_in, const int* in_sizes, int n_in,
                              void* d_out, int out_size, void* d_ws, size_t ws_size,
                              hipStream_t stream) {
    const int*   cap  = (const int*)d_in[0];
    const float* img  = (const float*)d_in[1];
    const float* Bemb = (const float*)d_in[2];
    const float* V_W  = (const float*)d_in[3];
    const float* V_b  = (const float*)d_in[4];
    const float* S_W  = (const float*)d_in[5];
    const float* S_b  = (const float*)d_in[6];
    const float* U_W  = (const float*)d_in[7];
    const float* U_b  = (const float*)d_in[8];
    const float* W_W  = (const float*)d_in[9];
    const float* W_b  = (const float*)d_in[10];
    const float* C_W  = (const float*)d_in[11];
    const float* C_b  = (const float*)d_in[12];
    const float* h0   = (const float*)d_in[13];
    const float* c0   = (const float*)d_in[14];

    char* ws = (char*)d_ws;
    ushort_t* mir = (ushort_t*)(ws);                       // 37.39 MB bf16 mirror
    ushort_t* X   = (ushort_t*)(ws + (size_t)(36u << 20)); // 2 MB  (2048x512)
    ushort_t* g1  = (ushort_t*)(ws + (size_t)(38u << 20)); // 8 MB  (2048x2048)
    ushort_t* g2  = (ushort_t*)(ws + (size_t)(46u << 20)); // 8 MB  (2048x2048)
    ushort_t* Hb  = (ushort_t*)(ws + (size_t)(54u << 20)); // 4 MB  (2048x1024)
    float*    cS  = (float*)   (ws + (size_t)(58u << 20)); // 256 KB (64x1024 f32)
    ushort_t* g3  = (ushort_t*)d_out;                      // 16 MB scratch, dead before stage F

    const ushort_t* V_Wb = mir;
    const ushort_t* S_Wb = mir + 1048576L;
    const ushort_t* U_Wb = mir + 2097152L;
    const ushort_t* W_Wb = mir + 4194304L;
    const ushort_t* C_Wb = mir + 8388608L;
    const ushort_t* h0b  = mir + 18628608L;

    cvt_all<<<9128, 256, 0, stream>>>(V_W, S_W, U_W, W_W, C_W, h0, mir);
    build_x<<<512, 256, 0, stream>>>(cap, img, Bemb, X);

    // Stage B: g1 = X (2048x512) * V_Wcat^T (2048x512) + V_b
    gemm_bt<<<dim3(16, 16, 1), 256, 0, stream>>>(X, 512, 0, V_Wb, 512, 0,
                                                 g1, 2048, 0, V_b, 0, 2048, 512, 0);
    // Stage C (per gate): g2[:, g] = g1[:, g] (2048x512) * S_W[g]^T (512x512) + S_b[g]
    gemm_bt<<<dim3(4, 16, 4), 256, 0, stream>>>(g1, 2048, 512, S_Wb, 512, 512 * 512,
                                                g2, 2048, 512, S_b, 512, 512, 512, 0);
    // Stage D (per gate): g3[:, g] = g2[:, g] (2048x512) * U_W[g]^T (1024x512) + U_b[g]
    gemm_bt<<<dim3(8, 16, 4), 256, 0, stream>>>(g2, 2048, 512, U_Wb, 512, 1024 * 512,
                                                g3, 4096, 1024, U_b, 1024, 1024, 512, 0);
    // Stage E: sequential scan (32 steps)
    for (int t = 0; t < Tdim; t++) {
        const ushort_t* hp = (t == 0) ? h0b : (Hb + (size_t)(t - 1) * Hdim);
        long lda = (t == 0) ? (long)Hdim : (long)(Tdim * Hdim);
        const float* cin = (t == 0) ? c0 : cS;
        lstm_step<<<64, 256, 0, stream>>>(hp, lda, W_Wb, W_b, g3, cin, cS, Hb, t);
    }
    // Stage F: out = Hb (2048x1024) * C_W^T (10000x1024) + C_b  (f32 out)
    gemm_bt<<<dim3(79, 16, 1), 256, 0, stream>>>(Hb, 1024, 0, C_Wb, 1024, 0,
                                                 d_out, 10000, 0, C_b, 0,
                                                 10000, 1024, 1);
}

// Round 4
// 575.203 us; speedup vs baseline: 1.1416x; 1.1416x over previous
//
#include <hip/hip_runtime.h>
#include <hip/hip_bf16.h>

typedef __attribute__((ext_vector_type(8))) __bf16 bf16x8;
typedef __attribute__((ext_vector_type(4))) float f32x4;
typedef unsigned short ushort_t;

#define Bdim 64
#define Tdim 32
#define Edim 512
#define Fdim 512
#define Hdim 1024
#define Vdim 10000
#define SCAN_BLOCKS 64

__device__ __forceinline__ float bf2f(ushort_t u) {
    unsigned int x = ((unsigned int)u) << 16;
    union { unsigned int i; float f; } c; c.i = x; return c.f;
}
__device__ __forceinline__ ushort_t f2bf(float f) {
    __hip_bfloat16 h = __float2bfloat16(f);
    union { __hip_bfloat16 h; ushort_t u; } c; c.h = h; return c.u;
}

__device__ __forceinline__ void gload_lds16(const void* g, void* l) {
    __builtin_amdgcn_global_load_lds(
        (const __attribute__((address_space(1))) unsigned int*)g,
        (__attribute__((address_space(3))) unsigned int*)l, 16, 0, 0);
}

// ---------------- Stage 0: f32 -> bf16 mirror of weights + h0; zero barrier ----------------
__global__ void cvt_all(const float* __restrict__ vw, const float* __restrict__ sw,
                        const float* __restrict__ uw, const float* __restrict__ ww,
                        const float* __restrict__ cw, const float* __restrict__ h0,
                        ushort_t* __restrict__ mir, unsigned int* __restrict__ bar) {
    if (blockIdx.x == 0 && threadIdx.x == 0)
        __hip_atomic_store(bar, 0u, __ATOMIC_RELAXED, __HIP_MEMORY_SCOPE_AGENT);
    long idx = ((long)blockIdx.x * blockDim.x + threadIdx.x) * 8;
    const float* src; long off;
    if      (idx <  1048576L) { src = vw; off = idx; }
    else if (idx <  2097152L) { src = sw; off = idx - 1048576L; }
    else if (idx <  4194304L) { src = uw; off = idx - 2097152L; }
    else if (idx <  8388608L) { src = ww; off = idx - 4194304L; }
    else if (idx < 18628608L) { src = cw; off = idx - 8388608L; }
    else if (idx < 18694144L) { src = h0; off = idx - 18628608L; }
    else return;
    float4 a = *(const float4*)(src + off);
    float4 b = *(const float4*)(src + off + 4);
    ushort_t o[8];
    o[0] = f2bf(a.x); o[1] = f2bf(a.y); o[2] = f2bf(a.z); o[3] = f2bf(a.w);
    o[4] = f2bf(b.x); o[5] = f2bf(b.y); o[6] = f2bf(b.z); o[7] = f2bf(b.w);
    *(int4*)(mir + idx) = *(const int4*)o;
}

// ---------------- Stage A: x = [img ; B_emb[captions[:, :-1]]], f32 -> bf16 ----------------
__global__ void build_x(const int* __restrict__ cap,
                        const float* __restrict__ img,
                        const float* __restrict__ emb,
                        ushort_t* __restrict__ X) {
    int idx = blockIdx.x * blockDim.x + threadIdx.x;
    int row = idx >> 6;
    int c8  = (idx & 63) << 3;
    int b = row >> 5, t = row & 31;
    const float* src = (t == 0) ? (img + (size_t)b * Edim)
                                : (emb + (size_t)cap[b * Tdim + (t - 1)] * Edim);
    float4 a  = *(const float4*)(src + c8);
    float4 bb = *(const float4*)(src + c8 + 4);
    ushort_t o[8];
    o[0] = f2bf(a.x);  o[1] = f2bf(a.y);  o[2] = f2bf(a.z);  o[3] = f2bf(a.w);
    o[4] = f2bf(bb.x); o[5] = f2bf(bb.y); o[6] = f2bf(bb.z); o[7] = f2bf(bb.w);
    *(int4*)(X + (size_t)row * Edim + c8) = *(const int4*)o;
}

// ---------------- Generic GEMM: C[m][n] = sum_k A[m][k]*Bt[n][k] + bias[n] ----------------
// T2 LDS XOR-swizzle: linear LDS dest + pre-swizzled global source + swizzled read.
// T1 XCD remap: contiguous bx strips per XCD (B-panel L2 locality).
// zpack=1: store [t][cg][g][hc][b] layout for lstm_scan (ldc/gsC ignored).
__launch_bounds__(256)
__global__ void gemm_bt(const ushort_t* __restrict__ A, long lda, long gsA,
                        const ushort_t* __restrict__ Bm, long ldb, long gsB,
                        void* __restrict__ Cv, long ldc, long gsC,
                        const float* __restrict__ bias, long gsBias,
                        int N, int K, int f32out, int zpack) {
    __shared__ ushort_t As[128 * 64];
    __shared__ ushort_t Bs[128 * 64];
    int z = blockIdx.z;
    A += (size_t)z * gsA; Bm += (size_t)z * gsB; bias += (size_t)z * gsBias;

    // T1: XCD-aware remap (per-z slab; slab sizes here are all %8==0)
    int nx = gridDim.x, ny = gridDim.y;
    int lin = blockIdx.x + nx * blockIdx.y;       // HW dispatch order within slab
    int per_xcd = (nx * ny) >> 3;
    int l2 = (lin & 7) * per_xcd + (lin >> 3);    // contiguous strip per XCD
    int bx = l2 / ny, by = l2 % ny;               // bx-major: same-XCD blocks share B-panel

    int tid = threadIdx.x;
    int w = tid >> 6, l = tid & 63;
    int wm = (w >> 1) * 64, wn = (w & 1) * 64;
    int m0 = by * 128, n0 = bx * 128;

    int srow = tid >> 3;          // 0..31 ; +32*j covers 128 rows
    int scol = (tid & 7) << 3;    // 0..56 step 8 elements

    int lane_r = l & 15;
    int lane_k = (l >> 4) << 3;

    f32x4 zero = {0.f, 0.f, 0.f, 0.f};
    f32x4 acc[4][4];
#pragma unroll
    for (int i = 0; i < 4; i++)
#pragma unroll
        for (int j = 0; j < 4; j++) acc[i][j] = zero;

    for (int k0 = 0; k0 < K; k0 += 64) {
#pragma unroll
        for (int j = 0; j < 4; j++) {
            int r = srow + j * 32;
            int sc = scol ^ ((r & 7) << 3);   // pre-swizzled source col
            gload_lds16(A + (size_t)(m0 + r) * lda + k0 + sc, &As[r * 64 + scol]);
        }
#pragma unroll
        for (int j = 0; j < 4; j++) {
            int r = srow + j * 32;
            int br = n0 + r; if (br > N - 1) br = N - 1;
            int sc = scol ^ ((r & 7) << 3);
            gload_lds16(Bm + (size_t)br * ldb + k0 + sc, &Bs[r * 64 + scol]);
        }
        __syncthreads();
#pragma unroll
        for (int kk = 0; kk < 64; kk += 32) {
            bf16x8 af[4], bfr[4];
#pragma unroll
            for (int i = 0; i < 4; i++) {
                int ar = wm + i * 16 + lane_r;
                af[i] = *(const bf16x8*)&As[ar * 64 + ((kk + lane_k) ^ ((ar & 7) << 3))];
            }
#pragma unroll
            for (int j = 0; j < 4; j++) {
                int br2 = wn + j * 16 + lane_r;
                bfr[j] = *(const bf16x8*)&Bs[br2 * 64 + ((kk + lane_k) ^ ((br2 & 7) << 3))];
            }
#pragma unroll
            for (int i = 0; i < 4; i++)
#pragma unroll
                for (int j = 0; j < 4; j++)
                    acc[i][j] = __builtin_amdgcn_mfma_f32_16x16x32_bf16(af[i], bfr[j], acc[i][j], 0, 0, 0);
        }
        __syncthreads();
    }

    int row_base = m0 + wm + ((l >> 4) << 2);
    int col_base = n0 + wn + lane_r;
#pragma unroll
    for (int j = 0; j < 4; j++) {
        int col = col_base + j * 16;
        if (col < N) {
            float bv = bias[col];
#pragma unroll
            for (int i = 0; i < 4; i++) {
#pragma unroll
                for (int r = 0; r < 4; r++) {
                    int row = row_base + i * 16 + r;
                    float v = acc[i][j][r] + bv;
                    if (zpack) {
                        int b = row >> 5, tt = row & 31;
                        size_t idx = (((size_t)(tt * 64 + (col >> 4)) * 4 + z) * 16
                                      + (col & 15)) * 64 + b;
                        ((ushort_t*)Cv)[idx] = f2bf(v);
                    } else if (f32out) {
                        ((float*)Cv)[(size_t)z * gsC + (size_t)row * ldc + col] = v;
                    } else {
                        ((ushort_t*)Cv)[(size_t)z * gsC + (size_t)row * ldc + col] = f2bf(v);
                    }
                }
            }
        }
    }
}

// ---------------- Stage E: persistent LSTM scan (COOPERATIVE launch) ----------------
// 64 blocks x 256 threads. Block cg owns h-cols [cg*16,cg*16+16) x 4 gates for ALL
// 64 batch rows (wave w covers batch rows [w*16,w*16+16)). W slice (64x1024) lives
// in LDS (XOR-swizzled) for all 32 steps; c-state in registers.
__launch_bounds__(256)
__global__ void lstm_scan(const ushort_t* __restrict__ Wm,   // bf16 [4*1024][1024]
                          const float* __restrict__ Wb,      // f32 [4][1024]
                          const ushort_t* __restrict__ zb,   // packed g3 [t][cg][g][hc][b]
                          const ushort_t* __restrict__ h0b,  // bf16 [64][1024]
                          const float* __restrict__ c0,      // f32 [64][1024]
                          ushort_t* __restrict__ Hb,         // bf16 [64][32][1024]
                          unsigned int* __restrict__ bar) {
    __shared__ ushort_t Ws[64 * 1024];   // 128 KiB
    int cg = blockIdx.x;
    int tid = threadIdx.x;
    int w = tid >> 6, l = tid & 63;
    int lane_r = l & 15, lane_kb = (l >> 4) << 3;

    // ---- prologue: stage W slice into LDS with 16B XOR swizzle (reg-staged) ----
    for (int e = tid * 8; e < 65536; e += 2048) {
        int rowl = e >> 10, ke = e & 1023;
        int g = rowl >> 4, hc = rowl & 15;
        const ushort_t* src = Wm + ((size_t)(g * Hdim + cg * 16 + hc)) * Hdim + ke;
        int dstb = rowl * 2048 + ((ke * 2) ^ ((rowl & 7) << 4));
        *(int4*)((char*)Ws + dstb) = *(const int4*)src;
    }
    int hcol = cg * 16 + lane_r;
    float wbv[4];
#pragma unroll
    for (int g = 0; g < 4; g++) wbv[g] = Wb[g * Hdim + hcol];
    int rb0 = w * 16 + ((l >> 4) << 2);   // first of this thread's 4 batch rows
    float cst[4];
#pragma unroll
    for (int r = 0; r < 4; r++) cst[r] = c0[(size_t)(rb0 + r) * Hdim + hcol];
    __syncthreads();

    int arow = w * 16 + lane_r;
    int swz = (lane_r & 7) << 4;

    for (int t = 0; t < Tdim; t++) {
        const ushort_t* hp = t ? (Hb + (size_t)(t - 1) * Hdim) : h0b;
        long hstr = t ? (long)(Tdim * Hdim) : (long)Hdim;

        // g3 loads for this step (4 gates x 4 batch rows, 8B each)
        ushort_t g3s[4][4];
        size_t zbase = ((size_t)t * 64 + cg) * 4096 + (size_t)lane_r * 64 + rb0;
#pragma unroll
        for (int g = 0; g < 4; g++)
            *(ushort4*)g3s[g] = *(const ushort4*)(zb + zbase + (size_t)g * 1024);

        f32x4 zero = {0.f, 0.f, 0.f, 0.f};
        f32x4 acc[4];
#pragma unroll
        for (int g = 0; g < 4; g++) acc[g] = zero;

        const ushort_t* ap = hp + (size_t)arow * hstr + lane_kb;
#pragma unroll 4
        for (int k0 = 0; k0 < Hdim; k0 += 32) {
            bf16x8 a = *(const bf16x8*)(ap + k0);
#pragma unroll
            for (int g = 0; g < 4; g++) {
                bf16x8 b = *(const bf16x8*)((const char*)Ws
                              + ((g * 16 + lane_r) * 2048 + (((k0 + lane_kb) * 2) ^ swz)));
                acc[g] = __builtin_amdgcn_mfma_f32_16x16x32_bf16(a, b, acc[g], 0, 0, 0);
            }
        }

#pragma unroll
        for (int r = 0; r < 4; r++) {
            float zi = acc[0][r] + wbv[0] + bf2f(g3s[0][r]);
            float zf = acc[1][r] + wbv[1] + bf2f(g3s[1][r]);
            float zo = acc[2][r] + wbv[2] + bf2f(g3s[2][r]);
            float zc = acc[3][r] + wbv[3] + bf2f(g3s[3][r]);
            float it = 1.f / (1.f + expf(-zi));
            float ft = 1.f / (1.f + expf(-zf));
            float ot = 1.f / (1.f + expf(-zo));
            float ct = tanhf(zc);
            float cn = ft * cst[r] + it * ct;
            cst[r] = cn;
            Hb[((size_t)(rb0 + r) * Tdim + t) * Hdim + hcol] = f2bf(ot * cn);
        }

        if (t < Tdim - 1) {
            __syncthreads();
            if (tid == 0) {
                __threadfence();   // write-back Hb (agent scope, cross-XCD)
                __hip_atomic_fetch_add(bar, 1u, __ATOMIC_RELEASE, __HIP_MEMORY_SCOPE_AGENT);
                unsigned int tgt = (unsigned int)SCAN_BLOCKS * (unsigned int)(t + 1);
                while (__hip_atomic_load(bar, __ATOMIC_RELAXED, __HIP_MEMORY_SCOPE_AGENT) < tgt)
                    __builtin_amdgcn_s_sleep(2);
                __threadfence();   // invalidate stale L1/L2 before reading others' Hb
            }
            __syncthreads();
        }
    }
}

extern "C" void kernel_launch(void* const* d_in, const int* in_sizes, int n_in,
                              void* d_out, int out_size, void* d_ws, size_t ws_size,
                              hipStream_t stream) {
    const int*   cap  = (const int*)d_in[0];
    const float* img  = (const float*)d_in[1];
    const float* Bemb = (const float*)d_in[2];
    const float* V_W  = (const float*)d_in[3];
    const float* V_b  = (const float*)d_in[4];
    const float* S_W  = (const float*)d_in[5];
    const float* S_b  = (const float*)d_in[6];
    const float* U_W  = (const float*)d_in[7];
    const float* U_b  = (const float*)d_in[8];
    const float* W_W  = (const float*)d_in[9];
    const float* W_b  = (const float*)d_in[10];
    const float* C_W  = (const float*)d_in[11];
    const float* C_b  = (const float*)d_in[12];
    const float* h0   = (const float*)d_in[13];
    const float* c0   = (const float*)d_in[14];

    char* ws = (char*)d_ws;
    ushort_t* mir = (ushort_t*)(ws);                       // 35.7 MiB bf16 mirror
    ushort_t* X   = (ushort_t*)(ws + (size_t)(36u << 20)); // 2 MiB
    ushort_t* g1  = (ushort_t*)(ws + (size_t)(38u << 20)); // 8 MiB
    ushort_t* g2  = (ushort_t*)(ws + (size_t)(46u << 20)); // 8 MiB
    ushort_t* Hb  = (ushort_t*)(ws + (size_t)(54u << 20)); // 4 MiB  [ends at 58 MiB]
    unsigned int* bar = (unsigned int*)(ws + (size_t)(58u << 20));
    ushort_t* zb  = (ushort_t*)d_out;                      // 16 MiB scratch, dead before stage F

    const ushort_t* V_Wb = mir;
    const ushort_t* S_Wb = mir + 1048576L;
    const ushort_t* U_Wb = mir + 2097152L;
    const ushort_t* W_Wb = mir + 4194304L;
    const ushort_t* C_Wb = mir + 8388608L;
    const ushort_t* h0b  = mir + 18628608L;

    cvt_all<<<9128, 256, 0, stream>>>(V_W, S_W, U_W, W_W, C_W, h0, mir, bar);
    build_x<<<512, 256, 0, stream>>>(cap, img, Bemb, X);

    // Stage B: g1 = X (2048x512) * V_Wcat^T (2048x512) + V_b
    gemm_bt<<<dim3(16, 16, 1), 256, 0, stream>>>(X, 512, 0, V_Wb, 512, 0,
                                                 g1, 2048, 0, V_b, 0, 2048, 512, 0, 0);
    // Stage C (per gate): g2[:, g] = g1[:, g] * S_W[g]^T + S_b[g]
    gemm_bt<<<dim3(4, 16, 4), 256, 0, stream>>>(g1, 2048, 512, S_Wb, 512, 512 * 512,
                                                g2, 2048, 512, S_b, 512, 512, 512, 0, 0);
    // Stage D (per gate): zb(packed) = g2[:, g] * U_W[g]^T + U_b[g]
    gemm_bt<<<dim3(8, 16, 4), 256, 0, stream>>>(g2, 2048, 512, U_Wb, 512, 1024 * 512,
                                                zb, 0, 0, U_b, 1024, 1024, 512, 0, 1);
    // Stage E: persistent scan — COOPERATIVE launch guarantees co-residency
    {
        const ushort_t* a0 = W_Wb; const float* a1 = W_b; const ushort_t* a2 = zb;
        const ushort_t* a3 = h0b;  const float* a4 = c0;  ushort_t* a5 = Hb;
        unsigned int* a6 = bar;
        void* sargs[7] = {(void*)&a0, (void*)&a1, (void*)&a2, (void*)&a3,
                          (void*)&a4, (void*)&a5, (void*)&a6};
        hipLaunchCooperativeKernel((const void*)lstm_scan, dim3(SCAN_BLOCKS), dim3(256),
                                   sargs, 0, stream);
    }
    // Stage F: out = Hb (2048x1024) * C_W^T (10000x1024) + C_b  (f32 out)
    gemm_bt<<<dim3(79, 16, 1), 256, 0, stream>>>(Hb, 1024, 0, C_Wb, 1024, 0,
                                                 d_out, 10000, 0, C_b, 0,
                                                 10000, 1024, 1, 0);
}

// Round 5
// 503.549 us; speedup vs baseline: 1.3040x; 1.1423x over previous
//
#include <hip/hip_runtime.h>
#include <hip/hip_bf16.h>

typedef __attribute__((ext_vector_type(8))) __bf16 bf16x8;
typedef __attribute__((ext_vector_type(4))) float f32x4;
typedef unsigned short ushort_t;

#define Bdim 64
#define Tdim 32
#define Edim 512
#define Fdim 512
#define Hdim 1024
#define Vdim 10000
#define SCAN_BLOCKS 64

__device__ __forceinline__ float bf2f(ushort_t u) {
    unsigned int x = ((unsigned int)u) << 16;
    union { unsigned int i; float f; } c; c.i = x; return c.f;
}
__device__ __forceinline__ ushort_t f2bf(float f) {
    __hip_bfloat16 h = __float2bfloat16(f);
    union { __hip_bfloat16 h; ushort_t u; } c; c.h = h; return c.u;
}

__device__ __forceinline__ void gload_lds16(const void* g, void* l) {
    __builtin_amdgcn_global_load_lds(
        (const __attribute__((address_space(1))) unsigned int*)g,
        (__attribute__((address_space(3))) unsigned int*)l, 16, 0, 0);
}

// write-through 2-byte store: visible device-wide once vmcnt-complete, no dirty L2 line
__device__ __forceinline__ void store_short_wt(ushort_t* p, ushort_t v) {
    asm volatile("global_store_short %0, %1, off sc0 sc1"
                 : : "v"(p), "v"((unsigned int)v) : "memory");
}

// ---------------- Stage 0: f32 -> bf16 mirror of weights + h0; zero barrier ----------------
__global__ void cvt_all(const float* __restrict__ vw, const float* __restrict__ sw,
                        const float* __restrict__ uw, const float* __restrict__ ww,
                        const float* __restrict__ cw, const float* __restrict__ h0,
                        ushort_t* __restrict__ mir, unsigned int* __restrict__ bar) {
    if (blockIdx.x == 0 && threadIdx.x == 0)
        __hip_atomic_store(bar, 0u, __ATOMIC_RELAXED, __HIP_MEMORY_SCOPE_AGENT);
    long idx = ((long)blockIdx.x * blockDim.x + threadIdx.x) * 8;
    const float* src; long off;
    if      (idx <  1048576L) { src = vw; off = idx; }
    else if (idx <  2097152L) { src = sw; off = idx - 1048576L; }
    else if (idx <  4194304L) { src = uw; off = idx - 2097152L; }
    else if (idx <  8388608L) { src = ww; off = idx - 4194304L; }
    else if (idx < 18628608L) { src = cw; off = idx - 8388608L; }
    else if (idx < 18694144L) { src = h0; off = idx - 18628608L; }
    else return;
    float4 a = *(const float4*)(src + off);
    float4 b = *(const float4*)(src + off + 4);
    ushort_t o[8];
    o[0] = f2bf(a.x); o[1] = f2bf(a.y); o[2] = f2bf(a.z); o[3] = f2bf(a.w);
    o[4] = f2bf(b.x); o[5] = f2bf(b.y); o[6] = f2bf(b.z); o[7] = f2bf(b.w);
    *(int4*)(mir + idx) = *(const int4*)o;
}

// ---------------- Stage A: x = [img ; B_emb[captions[:, :-1]]], f32 -> bf16 ----------------
__global__ void build_x(const int* __restrict__ cap,
                        const float* __restrict__ img,
                        const float* __restrict__ emb,
                        ushort_t* __restrict__ X) {
    int idx = blockIdx.x * blockDim.x + threadIdx.x;
    int row = idx >> 6;
    int c8  = (idx & 63) << 3;
    int b = row >> 5, t = row & 31;
    const float* src = (t == 0) ? (img + (size_t)b * Edim)
                                : (emb + (size_t)cap[b * Tdim + (t - 1)] * Edim);
    float4 a  = *(const float4*)(src + c8);
    float4 bb = *(const float4*)(src + c8 + 4);
    ushort_t o[8];
    o[0] = f2bf(a.x);  o[1] = f2bf(a.y);  o[2] = f2bf(a.z);  o[3] = f2bf(a.w);
    o[4] = f2bf(bb.x); o[5] = f2bf(bb.y); o[6] = f2bf(bb.z); o[7] = f2bf(bb.w);
    *(int4*)(X + (size_t)row * Edim + c8) = *(const int4*)o;
}

// ---------------- Generic GEMM: C[m][n] = sum_k A[m][k]*Bt[n][k] + bias[n] ----------------
// T2 LDS XOR-swizzle: linear LDS dest + pre-swizzled global source + swizzled read.
// T1 XCD remap: contiguous bx strips per XCD (B-panel L2 locality).
// zpack=1: store [t][cg][g][hc][b] layout for lstm_scan (ldc/gsC ignored).
__launch_bounds__(256)
__global__ void gemm_bt(const ushort_t* __restrict__ A, long lda, long gsA,
                        const ushort_t* __restrict__ Bm, long ldb, long gsB,
                        void* __restrict__ Cv, long ldc, long gsC,
                        const float* __restrict__ bias, long gsBias,
                        int N, int K, int f32out, int zpack) {
    __shared__ ushort_t As[128 * 64];
    __shared__ ushort_t Bs[128 * 64];
    int z = blockIdx.z;
    A += (size_t)z * gsA; Bm += (size_t)z * gsB; bias += (size_t)z * gsBias;

    // T1: XCD-aware remap (per-z slab; slab sizes here are all %8==0)
    int nx = gridDim.x, ny = gridDim.y;
    int lin = blockIdx.x + nx * blockIdx.y;       // HW dispatch order within slab
    int per_xcd = (nx * ny) >> 3;
    int l2 = (lin & 7) * per_xcd + (lin >> 3);    // contiguous strip per XCD
    int bx = l2 / ny, by = l2 % ny;               // bx-major: same-XCD blocks share B-panel

    int tid = threadIdx.x;
    int w = tid >> 6, l = tid & 63;
    int wm = (w >> 1) * 64, wn = (w & 1) * 64;
    int m0 = by * 128, n0 = bx * 128;

    int srow = tid >> 3;          // 0..31 ; +32*j covers 128 rows
    int scol = (tid & 7) << 3;    // 0..56 step 8 elements

    int lane_r = l & 15;
    int lane_k = (l >> 4) << 3;

    f32x4 zero = {0.f, 0.f, 0.f, 0.f};
    f32x4 acc[4][4];
#pragma unroll
    for (int i = 0; i < 4; i++)
#pragma unroll
        for (int j = 0; j < 4; j++) acc[i][j] = zero;

    for (int k0 = 0; k0 < K; k0 += 64) {
#pragma unroll
        for (int j = 0; j < 4; j++) {
            int r = srow + j * 32;
            int sc = scol ^ ((r & 7) << 3);   // pre-swizzled source col
            gload_lds16(A + (size_t)(m0 + r) * lda + k0 + sc, &As[r * 64 + scol]);
        }
#pragma unroll
        for (int j = 0; j < 4; j++) {
            int r = srow + j * 32;
            int br = n0 + r; if (br > N - 1) br = N - 1;
            int sc = scol ^ ((r & 7) << 3);
            gload_lds16(Bm + (size_t)br * ldb + k0 + sc, &Bs[r * 64 + scol]);
        }
        __syncthreads();
#pragma unroll
        for (int kk = 0; kk < 64; kk += 32) {
            bf16x8 af[4], bfr[4];
#pragma unroll
            for (int i = 0; i < 4; i++) {
                int ar = wm + i * 16 + lane_r;
                af[i] = *(const bf16x8*)&As[ar * 64 + ((kk + lane_k) ^ ((ar & 7) << 3))];
            }
#pragma unroll
            for (int j = 0; j < 4; j++) {
                int br2 = wn + j * 16 + lane_r;
                bfr[j] = *(const bf16x8*)&Bs[br2 * 64 + ((kk + lane_k) ^ ((br2 & 7) << 3))];
            }
#pragma unroll
            for (int i = 0; i < 4; i++)
#pragma unroll
                for (int j = 0; j < 4; j++)
                    acc[i][j] = __builtin_amdgcn_mfma_f32_16x16x32_bf16(af[i], bfr[j], acc[i][j], 0, 0, 0);
        }
        __syncthreads();
    }

    int row_base = m0 + wm + ((l >> 4) << 2);
    int col_base = n0 + wn + lane_r;
#pragma unroll
    for (int j = 0; j < 4; j++) {
        int col = col_base + j * 16;
        if (col < N) {
            float bv = bias[col];
#pragma unroll
            for (int i = 0; i < 4; i++) {
#pragma unroll
                for (int r = 0; r < 4; r++) {
                    int row = row_base + i * 16 + r;
                    float v = acc[i][j][r] + bv;
                    if (zpack) {
                        int b = row >> 5, tt = row & 31;
                        size_t idx = (((size_t)(tt * 64 + (col >> 4)) * 4 + z) * 16
                                      + (col & 15)) * 64 + b;
                        ((ushort_t*)Cv)[idx] = f2bf(v);
                    } else if (f32out) {
                        ((float*)Cv)[(size_t)z * gsC + (size_t)row * ldc + col] = v;
                    } else {
                        ((ushort_t*)Cv)[(size_t)z * gsC + (size_t)row * ldc + col] = f2bf(v);
                    }
                }
            }
        }
    }
}

// ---------------- Stage E: persistent LSTM scan (COOPERATIVE launch) ----------------
// 64 blocks x 256 threads. Block cg owns h-cols [cg*16,cg*16+16) x 4 gates for ALL
// 64 batch rows. W slice (64x1024) in LDS (XOR-swizzled) for all 32 steps; c-state
// in registers. h handoff: write-through stores (sc0 sc1) -> step-t addresses are
// never in any reader cache -> no wbl2/inv needed; barrier = relaxed agent atomics.
__launch_bounds__(256)
__global__ void lstm_scan(const ushort_t* __restrict__ Wm,   // bf16 [4*1024][1024]
                          const float* __restrict__ Wb,      // f32 [4][1024]
                          const ushort_t* __restrict__ zb,   // packed g3 [t][cg][g][hc][b]
                          const ushort_t* __restrict__ h0b,  // bf16 [64][1024]
                          const float* __restrict__ c0,      // f32 [64][1024]
                          ushort_t* __restrict__ Hb,         // bf16 [64][32][1024]
                          unsigned int* __restrict__ bar) {
    __shared__ ushort_t Ws[64 * 1024];   // 128 KiB
    int cg = blockIdx.x;
    int tid = threadIdx.x;
    int w = tid >> 6, l = tid & 63;
    int lane_r = l & 15, lane_kb = (l >> 4) << 3;

    // ---- prologue: stage W slice into LDS with 16B XOR swizzle (reg-staged) ----
    for (int e = tid * 8; e < 65536; e += 2048) {
        int rowl = e >> 10, ke = e & 1023;
        int g = rowl >> 4, hc = rowl & 15;
        const ushort_t* src = Wm + ((size_t)(g * Hdim + cg * 16 + hc)) * Hdim + ke;
        int dstb = rowl * 2048 + ((ke * 2) ^ ((rowl & 7) << 4));
        *(int4*)((char*)Ws + dstb) = *(const int4*)src;
    }
    int hcol = cg * 16 + lane_r;
    float wbv[4];
#pragma unroll
    for (int g = 0; g < 4; g++) wbv[g] = Wb[g * Hdim + hcol];
    int rb0 = w * 16 + ((l >> 4) << 2);   // first of this thread's 4 batch rows
    float cst[4];
#pragma unroll
    for (int r = 0; r < 4; r++) cst[r] = c0[(size_t)(rb0 + r) * Hdim + hcol];
    __syncthreads();

    int arow = w * 16 + lane_r;
    int swz = (lane_r & 7) << 4;

    for (int t = 0; t < Tdim; t++) {
        const ushort_t* hp = t ? (Hb + (size_t)(t - 1) * Hdim) : h0b;
        long hstr = t ? (long)(Tdim * Hdim) : (long)Hdim;

        // g3 loads for this step (4 gates x 4 batch rows, 8B each)
        ushort_t g3s[4][4];
        size_t zbase = ((size_t)t * 64 + cg) * 4096 + (size_t)lane_r * 64 + rb0;
#pragma unroll
        for (int g = 0; g < 4; g++)
            *(ushort4*)g3s[g] = *(const ushort4*)(zb + zbase + (size_t)g * 1024);

        f32x4 zero = {0.f, 0.f, 0.f, 0.f};
        f32x4 acc[4];
#pragma unroll
        for (int g = 0; g < 4; g++) acc[g] = zero;

        const ushort_t* ap = hp + (size_t)arow * hstr + lane_kb;
#pragma unroll 4
        for (int k0 = 0; k0 < Hdim; k0 += 32) {
            bf16x8 a = *(const bf16x8*)(ap + k0);
#pragma unroll
            for (int g = 0; g < 4; g++) {
                bf16x8 b = *(const bf16x8*)((const char*)Ws
                              + ((g * 16 + lane_r) * 2048 + (((k0 + lane_kb) * 2) ^ swz)));
                acc[g] = __builtin_amdgcn_mfma_f32_16x16x32_bf16(a, b, acc[g], 0, 0, 0);
            }
        }

#pragma unroll
        for (int r = 0; r < 4; r++) {
            float zi = acc[0][r] + wbv[0] + bf2f(g3s[0][r]);
            float zf = acc[1][r] + wbv[1] + bf2f(g3s[1][r]);
            float zo = acc[2][r] + wbv[2] + bf2f(g3s[2][r]);
            float zc = acc[3][r] + wbv[3] + bf2f(g3s[3][r]);
            float it = 1.f / (1.f + expf(-zi));
            float ft = 1.f / (1.f + expf(-zf));
            float ot = 1.f / (1.f + expf(-zo));
            float ct = tanhf(zc);
            float cn = ft * cst[r] + it * ct;
            cst[r] = cn;
            // write-through: visible at memory-side once vmcnt-complete
            store_short_wt(Hb + ((size_t)(rb0 + r) * Tdim + t) * Hdim + hcol,
                           f2bf(ot * cn));
        }

        if (t < Tdim - 1) {
            // drain this wave's write-through stores, then block-arrive
            asm volatile("s_waitcnt vmcnt(0)" ::: "memory");
            __syncthreads();
            if (tid == 0) {
                __hip_atomic_fetch_add(bar, 1u, __ATOMIC_RELAXED, __HIP_MEMORY_SCOPE_AGENT);
                unsigned int tgt = (unsigned int)SCAN_BLOCKS * (unsigned int)(t + 1);
                while (__hip_atomic_load(bar, __ATOMIC_RELAXED, __HIP_MEMORY_SCOPE_AGENT) < tgt)
                    __builtin_amdgcn_s_sleep(1);
                asm volatile("" ::: "memory");
            }
            __syncthreads();
        }
    }
}

extern "C" void kernel_launch(void* const* d_in, const int* in_sizes, int n_in,
                              void* d_out, int out_size, void* d_ws, size_t ws_size,
                              hipStream_t stream) {
    const int*   cap  = (const int*)d_in[0];
    const float* img  = (const float*)d_in[1];
    const float* Bemb = (const float*)d_in[2];
    const float* V_W  = (const float*)d_in[3];
    const float* V_b  = (const float*)d_in[4];
    const float* S_W  = (const float*)d_in[5];
    const float* S_b  = (const float*)d_in[6];
    const float* U_W  = (const float*)d_in[7];
    const float* U_b  = (const float*)d_in[8];
    const float* W_W  = (const float*)d_in[9];
    const float* W_b  = (const float*)d_in[10];
    const float* C_W  = (const float*)d_in[11];
    const float* C_b  = (const float*)d_in[12];
    const float* h0   = (const float*)d_in[13];
    const float* c0   = (const float*)d_in[14];

    char* ws = (char*)d_ws;
    ushort_t* mir = (ushort_t*)(ws);                       // 35.7 MiB bf16 mirror
    ushort_t* X   = (ushort_t*)(ws + (size_t)(36u << 20)); // 2 MiB
    ushort_t* g1  = (ushort_t*)(ws + (size_t)(38u << 20)); // 8 MiB
    ushort_t* g2  = (ushort_t*)(ws + (size_t)(46u << 20)); // 8 MiB
    ushort_t* Hb  = (ushort_t*)(ws + (size_t)(54u << 20)); // 4 MiB  [ends at 58 MiB]
    unsigned int* bar = (unsigned int*)(ws + (size_t)(58u << 20));
    ushort_t* zb  = (ushort_t*)d_out;                      // 16 MiB scratch, dead before stage F

    const ushort_t* V_Wb = mir;
    const ushort_t* S_Wb = mir + 1048576L;
    const ushort_t* U_Wb = mir + 2097152L;
    const ushort_t* W_Wb = mir + 4194304L;
    const ushort_t* C_Wb = mir + 8388608L;
    const ushort_t* h0b  = mir + 18628608L;

    cvt_all<<<9128, 256, 0, stream>>>(V_W, S_W, U_W, W_W, C_W, h0, mir, bar);
    build_x<<<512, 256, 0, stream>>>(cap, img, Bemb, X);

    // Stage B: g1 = X (2048x512) * V_Wcat^T (2048x512) + V_b
    gemm_bt<<<dim3(16, 16, 1), 256, 0, stream>>>(X, 512, 0, V_Wb, 512, 0,
                                                 g1, 2048, 0, V_b, 0, 2048, 512, 0, 0);
    // Stage C (per gate): g2[:, g] = g1[:, g] * S_W[g]^T + S_b[g]
    gemm_bt<<<dim3(4, 16, 4), 256, 0, stream>>>(g1, 2048, 512, S_Wb, 512, 512 * 512,
                                                g2, 2048, 512, S_b, 512, 512, 512, 0, 0);
    // Stage D (per gate): zb(packed) = g2[:, g] * U_W[g]^T + U_b[g]
    gemm_bt<<<dim3(8, 16, 4), 256, 0, stream>>>(g2, 2048, 512, U_Wb, 512, 1024 * 512,
                                                zb, 0, 0, U_b, 1024, 1024, 512, 0, 1);
    // Stage E: persistent scan — COOPERATIVE launch guarantees co-residency
    {
        const ushort_t* a0 = W_Wb; const float* a1 = W_b; const ushort_t* a2 = zb;
        const ushort_t* a3 = h0b;  const float* a4 = c0;  ushort_t* a5 = Hb;
        unsigned int* a6 = bar;
        void* sargs[7] = {(void*)&a0, (void*)&a1, (void*)&a2, (void*)&a3,
                          (void*)&a4, (void*)&a5, (void*)&a6};
        hipLaunchCooperativeKernel((const void*)lstm_scan, dim3(SCAN_BLOCKS), dim3(256),
                                   sargs, 0, stream);
    }
    // Stage F: out = Hb (2048x1024) * C_W^T (10000x1024) + C_b  (f32 out)
    gemm_bt<<<dim3(79, 16, 1), 256, 0, stream>>>(Hb, 1024, 0, C_Wb, 1024, 0,
                                                 d_out, 10000, 0, C_b, 0,
                                                 10000, 1024, 1, 0);
}

// Round 6
// 425.142 us; speedup vs baseline: 1.5445x; 1.1844x over previous
//
#include <hip/hip_runtime.h>
#include <hip/hip_bf16.h>

typedef __attribute__((ext_vector_type(8))) __bf16 bf16x8;
typedef __attribute__((ext_vector_type(4))) float f32x4;
typedef unsigned short ushort_t;

#define Bdim 64
#define Tdim 32
#define Edim 512
#define Fdim 512
#define Hdim 1024
#define Vdim 10000
#define SCAN_BLOCKS 64

__device__ __forceinline__ float bf2f(ushort_t u) {
    unsigned int x = ((unsigned int)u) << 16;
    union { unsigned int i; float f; } c; c.i = x; return c.f;
}
__device__ __forceinline__ ushort_t f2bf(float f) {
    __hip_bfloat16 h = __float2bfloat16(f);
    union { __hip_bfloat16 h; ushort_t u; } c; c.h = h; return c.u;
}

__device__ __forceinline__ void gload_lds16(const void* g, void* l) {
    __builtin_amdgcn_global_load_lds(
        (const __attribute__((address_space(1))) unsigned int*)g,
        (__attribute__((address_space(3))) unsigned int*)l, 16, 0, 0);
}

// write-through stores: visible device-wide once vmcnt-complete, no dirty local-L2 line
__device__ __forceinline__ void store_short_wt(ushort_t* p, ushort_t v) {
    asm volatile("global_store_short %0, %1, off sc0 sc1"
                 : : "v"(p), "v"((unsigned int)v) : "memory");
}
__device__ __forceinline__ void store_uint_wt(unsigned int* p, unsigned int v) {
    asm volatile("global_store_dword %0, %1, off sc0 sc1"
                 : : "v"(p), "v"(v) : "memory");
}

// ---------------- Stage 0: f32 -> bf16 mirror of weights + h0; zero flags ----------------
__global__ void cvt_all(const float* __restrict__ vw, const float* __restrict__ sw,
                        const float* __restrict__ uw, const float* __restrict__ ww,
                        const float* __restrict__ cw, const float* __restrict__ h0,
                        ushort_t* __restrict__ mir, unsigned int* __restrict__ flg) {
    if (blockIdx.x == 0) {   // zero flags[32][64] (8 KiB)
        int4 zz = {0, 0, 0, 0};
        ((int4*)flg)[threadIdx.x * 2 + 0] = zz;
        ((int4*)flg)[threadIdx.x * 2 + 1] = zz;
    }
    long idx = ((long)blockIdx.x * blockDim.x + threadIdx.x) * 8;
    const float* src; long off;
    if      (idx <  1048576L) { src = vw; off = idx; }
    else if (idx <  2097152L) { src = sw; off = idx - 1048576L; }
    else if (idx <  4194304L) { src = uw; off = idx - 2097152L; }
    else if (idx <  8388608L) { src = ww; off = idx - 4194304L; }
    else if (idx < 18628608L) { src = cw; off = idx - 8388608L; }
    else if (idx < 18694144L) { src = h0; off = idx - 18628608L; }
    else return;
    float4 a = *(const float4*)(src + off);
    float4 b = *(const float4*)(src + off + 4);
    ushort_t o[8];
    o[0] = f2bf(a.x); o[1] = f2bf(a.y); o[2] = f2bf(a.z); o[3] = f2bf(a.w);
    o[4] = f2bf(b.x); o[5] = f2bf(b.y); o[6] = f2bf(b.z); o[7] = f2bf(b.w);
    *(int4*)(mir + idx) = *(const int4*)o;
}

// ---------------- Stage A: x = [img ; B_emb[captions[:, :-1]]], f32 -> bf16 ----------------
__global__ void build_x(const int* __restrict__ cap,
                        const float* __restrict__ img,
                        const float* __restrict__ emb,
                        ushort_t* __restrict__ X) {
    int idx = blockIdx.x * blockDim.x + threadIdx.x;
    int row = idx >> 6;
    int c8  = (idx & 63) << 3;
    int b = row >> 5, t = row & 31;
    const float* src = (t == 0) ? (img + (size_t)b * Edim)
                                : (emb + (size_t)cap[b * Tdim + (t - 1)] * Edim);
    float4 a  = *(const float4*)(src + c8);
    float4 bb = *(const float4*)(src + c8 + 4);
    ushort_t o[8];
    o[0] = f2bf(a.x);  o[1] = f2bf(a.y);  o[2] = f2bf(a.z);  o[3] = f2bf(a.w);
    o[4] = f2bf(bb.x); o[5] = f2bf(bb.y); o[6] = f2bf(bb.z); o[7] = f2bf(bb.w);
    *(int4*)(X + (size_t)row * Edim + c8) = *(const int4*)o;
}

// ---------------- Generic GEMM: C[m][n] = sum_k A[m][k]*Bt[n][k] + bias[n] ----------------
// T2 LDS XOR-swizzle; T1 XCD remap; zpack: [t][cg][g][hc][b] layout for lstm_scan.
// aswap=1: logical A-row (b*32+t) is stored at physical row (t*64+b)  (Hbt layout).
__launch_bounds__(256)
__global__ void gemm_bt(const ushort_t* __restrict__ A, long lda, long gsA,
                        const ushort_t* __restrict__ Bm, long ldb, long gsB,
                        void* __restrict__ Cv, long ldc, long gsC,
                        const float* __restrict__ bias, long gsBias,
                        int N, int K, int f32out, int zpack, int aswap) {
    __shared__ ushort_t As[128 * 64];
    __shared__ ushort_t Bs[128 * 64];
    int z = blockIdx.z;
    A += (size_t)z * gsA; Bm += (size_t)z * gsB; bias += (size_t)z * gsBias;

    // T1: XCD-aware remap (per-z slab; slab sizes here are all %8==0)
    int nx = gridDim.x, ny = gridDim.y;
    int lin = blockIdx.x + nx * blockIdx.y;
    int per_xcd = (nx * ny) >> 3;
    int l2 = (lin & 7) * per_xcd + (lin >> 3);
    int bx = l2 / ny, by = l2 % ny;

    int tid = threadIdx.x;
    int w = tid >> 6, l = tid & 63;
    int wm = (w >> 1) * 64, wn = (w & 1) * 64;
    int m0 = by * 128, n0 = bx * 128;

    int srow = tid >> 3;
    int scol = (tid & 7) << 3;

    int lane_r = l & 15;
    int lane_k = (l >> 4) << 3;

    f32x4 zero = {0.f, 0.f, 0.f, 0.f};
    f32x4 acc[4][4];
#pragma unroll
    for (int i = 0; i < 4; i++)
#pragma unroll
        for (int j = 0; j < 4; j++) acc[i][j] = zero;

    for (int k0 = 0; k0 < K; k0 += 64) {
#pragma unroll
        for (int j = 0; j < 4; j++) {
            int r = srow + j * 32;
            int pr = m0 + r;
            if (aswap) pr = ((pr & 31) << 6) + (pr >> 5);
            int sc = scol ^ ((r & 7) << 3);
            gload_lds16(A + (size_t)pr * lda + k0 + sc, &As[r * 64 + scol]);
        }
#pragma unroll
        for (int j = 0; j < 4; j++) {
            int r = srow + j * 32;
            int br = n0 + r; if (br > N - 1) br = N - 1;
            int sc = scol ^ ((r & 7) << 3);
            gload_lds16(Bm + (size_t)br * ldb + k0 + sc, &Bs[r * 64 + scol]);
        }
        __syncthreads();
#pragma unroll
        for (int kk = 0; kk < 64; kk += 32) {
            bf16x8 af[4], bfr[4];
#pragma unroll
            for (int i = 0; i < 4; i++) {
                int ar = wm + i * 16 + lane_r;
                af[i] = *(const bf16x8*)&As[ar * 64 + ((kk + lane_k) ^ ((ar & 7) << 3))];
            }
#pragma unroll
            for (int j = 0; j < 4; j++) {
                int br2 = wn + j * 16 + lane_r;
                bfr[j] = *(const bf16x8*)&Bs[br2 * 64 + ((kk + lane_k) ^ ((br2 & 7) << 3))];
            }
#pragma unroll
            for (int i = 0; i < 4; i++)
#pragma unroll
                for (int j = 0; j < 4; j++)
                    acc[i][j] = __builtin_amdgcn_mfma_f32_16x16x32_bf16(af[i], bfr[j], acc[i][j], 0, 0, 0);
        }
        __syncthreads();
    }

    int row_base = m0 + wm + ((l >> 4) << 2);
    int col_base = n0 + wn + lane_r;
#pragma unroll
    for (int j = 0; j < 4; j++) {
        int col = col_base + j * 16;
        if (col < N) {
            float bv = bias[col];
#pragma unroll
            for (int i = 0; i < 4; i++) {
#pragma unroll
                for (int r = 0; r < 4; r++) {
                    int row = row_base + i * 16 + r;
                    float v = acc[i][j][r] + bv;
                    if (zpack) {
                        int b = row >> 5, tt = row & 31;
                        size_t idx = (((size_t)(tt * 64 + (col >> 4)) * 4 + z) * 16
                                      + (col & 15)) * 64 + b;
                        ((ushort_t*)Cv)[idx] = f2bf(v);
                    } else if (f32out) {
                        ((float*)Cv)[(size_t)z * gsC + (size_t)row * ldc + col] = v;
                    } else {
                        ((ushort_t*)Cv)[(size_t)z * gsC + (size_t)row * ldc + col] = f2bf(v);
                    }
                }
            }
        }
    }
}

// ---------------- Stage E: persistent LSTM scan, flag-based dataflow ----------------
// 64 blocks x 256 threads (cooperative: co-residency guaranteed). Block cg owns
// h-cols [cg*16,cg*16+16) x 4 gates for all 64 batch rows. W slice in LDS all 32
// steps; c in registers. Handoff: write-through h stores + per-producer flags;
// readers poll lane-parallel (64 flags in one load) — no RMW, no grid barrier.
__launch_bounds__(256)
__global__ void lstm_scan(const ushort_t* __restrict__ Wm,   // bf16 [4*1024][1024]
                          const float* __restrict__ Wb,      // f32 [4][1024]
                          const ushort_t* __restrict__ zb,   // packed g3 [t][cg][g][hc][b]
                          const ushort_t* __restrict__ h0b,  // bf16 [64][1024]
                          const float* __restrict__ c0,      // f32 [64][1024]
                          ushort_t* __restrict__ Hbt,        // bf16 [t][64][1024]
                          unsigned int* __restrict__ flags) { // [32][64]
    __shared__ ushort_t Ws[64 * 1024];   // 128 KiB
    int cg = blockIdx.x;
    int tid = threadIdx.x;
    int w = tid >> 6, l = tid & 63;
    int lane_r = l & 15, lane_kb = (l >> 4) << 3;

    // ---- prologue: stage W slice into LDS with 16B XOR swizzle (reg-staged) ----
    for (int e = tid * 8; e < 65536; e += 2048) {
        int rowl = e >> 10, ke = e & 1023;
        int g = rowl >> 4, hc = rowl & 15;
        const ushort_t* src = Wm + ((size_t)(g * Hdim + cg * 16 + hc)) * Hdim + ke;
        int dstb = rowl * 2048 + ((ke * 2) ^ ((rowl & 7) << 4));
        *(int4*)((char*)Ws + dstb) = *(const int4*)src;
    }
    int hcol = cg * 16 + lane_r;
    float wbv[4];
#pragma unroll
    for (int g = 0; g < 4; g++) wbv[g] = Wb[g * Hdim + hcol];
    int rb0 = w * 16 + ((l >> 4) << 2);   // first of this thread's 4 batch rows
    float cst[4];
#pragma unroll
    for (int r = 0; r < 4; r++) cst[r] = c0[(size_t)(rb0 + r) * Hdim + hcol];
    __syncthreads();

    int arow = w * 16 + lane_r;
    int swz = (lane_r & 7) << 4;
    int rot = cg & 31;                    // staggered k-start spreads the all-to-all

    for (int t = 0; t < Tdim; t++) {
        // g3 loads for this step (independent of h) — issue before the poll
        ushort_t g3s[4][4];
        size_t zbase = ((size_t)t * 64 + cg) * 4096 + (size_t)lane_r * 64 + rb0;
#pragma unroll
        for (int g = 0; g < 4; g++)
            *(ushort4*)g3s[g] = *(const ushort4*)(zb + zbase + (size_t)g * 1024);

        // wait for ALL step-(t-1) producers: lane l watches flags[t-1][l]
        if (t > 0) {
            const unsigned int* fp = flags + (size_t)(t - 1) * 64 + l;
            unsigned int v;
            do {
                v = __hip_atomic_load(fp, __ATOMIC_RELAXED, __HIP_MEMORY_SCOPE_AGENT);
            } while (__ballot(v != 0) != 0xFFFFFFFFFFFFFFFFull);
        }

        const ushort_t* hp = t ? (Hbt + (size_t)(t - 1) * (Bdim * Hdim)) : h0b;
        const ushort_t* ap = hp + (size_t)arow * Hdim + lane_kb;

        f32x4 zero = {0.f, 0.f, 0.f, 0.f};
        f32x4 acc[4];
#pragma unroll
        for (int g = 0; g < 4; g++) acc[g] = zero;

        // 2-deep pipelined k-loop, rotated start
        bf16x8 a_cur = *(const bf16x8*)(ap + rot * 32);
#pragma unroll
        for (int d = 0; d < 32; d++) {
            bf16x8 a_nxt;
            if (d < 31) {
                int k1 = ((d + 1 + rot) & 31) * 32;
                a_nxt = *(const bf16x8*)(ap + k1);
            }
            int kc = ((d + rot) & 31) * 32;
#pragma unroll
            for (int g = 0; g < 4; g++) {
                bf16x8 b = *(const bf16x8*)((const char*)Ws
                              + ((g * 16 + lane_r) * 2048 + (((kc + lane_kb) * 2) ^ swz)));
                acc[g] = __builtin_amdgcn_mfma_f32_16x16x32_bf16(a_cur, b, acc[g], 0, 0, 0);
            }
            if (d < 31) a_cur = a_nxt;
        }

#pragma unroll
        for (int r = 0; r < 4; r++) {
            float zi = acc[0][r] + wbv[0] + bf2f(g3s[0][r]);
            float zf = acc[1][r] + wbv[1] + bf2f(g3s[1][r]);
            float zo = acc[2][r] + wbv[2] + bf2f(g3s[2][r]);
            float zc = acc[3][r] + wbv[3] + bf2f(g3s[3][r]);
            float it = 1.f / (1.f + expf(-zi));
            float ft = 1.f / (1.f + expf(-zf));
            float ot = 1.f / (1.f + expf(-zo));
            float ct = tanhf(zc);
            float cn = ft * cst[r] + it * ct;
            cst[r] = cn;
            store_short_wt(Hbt + (size_t)t * (Bdim * Hdim) + (size_t)(rb0 + r) * Hdim + hcol,
                           f2bf(ot * cn));
        }

        // drain this wave's h stores, block-arrive, publish own flag (plain WT store)
        asm volatile("s_waitcnt vmcnt(0)" ::: "memory");
        __syncthreads();
        if (tid == 0) store_uint_wt(flags + (size_t)t * 64 + cg, 1u);
    }
}

extern "C" void kernel_launch(void* const* d_in, const int* in_sizes, int n_in,
                              void* d_out, int out_size, void* d_ws, size_t ws_size,
                              hipStream_t stream) {
    const int*   cap  = (const int*)d_in[0];
    const float* img  = (const float*)d_in[1];
    const float* Bemb = (const float*)d_in[2];
    const float* V_W  = (const float*)d_in[3];
    const float* V_b  = (const float*)d_in[4];
    const float* S_W  = (const float*)d_in[5];
    const float* S_b  = (const float*)d_in[6];
    const float* U_W  = (const float*)d_in[7];
    const float* U_b  = (const float*)d_in[8];
    const float* W_W  = (const float*)d_in[9];
    const float* W_b  = (const float*)d_in[10];
    const float* C_W  = (const float*)d_in[11];
    const float* C_b  = (const float*)d_in[12];
    const float* h0   = (const float*)d_in[13];
    const float* c0   = (const float*)d_in[14];

    char* ws = (char*)d_ws;
    ushort_t* mir = (ushort_t*)(ws);                       // 35.7 MiB bf16 mirror
    ushort_t* X   = (ushort_t*)(ws + (size_t)(36u << 20)); // 2 MiB
    ushort_t* g1  = (ushort_t*)(ws + (size_t)(38u << 20)); // 8 MiB
    ushort_t* g2  = (ushort_t*)(ws + (size_t)(46u << 20)); // 8 MiB
    ushort_t* Hbt = (ushort_t*)(ws + (size_t)(54u << 20)); // 4 MiB [t][b][h]
    unsigned int* flags = (unsigned int*)(ws + (size_t)(58u << 20)); // 8 KiB
    ushort_t* zb  = (ushort_t*)d_out;                      // 16 MiB scratch, dead before stage F

    const ushort_t* V_Wb = mir;
    const ushort_t* S_Wb = mir + 1048576L;
    const ushort_t* U_Wb = mir + 2097152L;
    const ushort_t* W_Wb = mir + 4194304L;
    const ushort_t* C_Wb = mir + 8388608L;
    const ushort_t* h0b  = mir + 18628608L;

    cvt_all<<<9128, 256, 0, stream>>>(V_W, S_W, U_W, W_W, C_W, h0, mir, flags);
    build_x<<<512, 256, 0, stream>>>(cap, img, Bemb, X);

    // Stage B: g1 = X (2048x512) * V_Wcat^T (2048x512) + V_b
    gemm_bt<<<dim3(16, 16, 1), 256, 0, stream>>>(X, 512, 0, V_Wb, 512, 0,
                                                 g1, 2048, 0, V_b, 0, 2048, 512, 0, 0, 0);
    // Stage C (per gate): g2[:, g] = g1[:, g] * S_W[g]^T + S_b[g]
    gemm_bt<<<dim3(4, 16, 4), 256, 0, stream>>>(g1, 2048, 512, S_Wb, 512, 512 * 512,
                                                g2, 2048, 512, S_b, 512, 512, 512, 0, 0, 0);
    // Stage D (per gate): zb(packed) = g2[:, g] * U_W[g]^T + U_b[g]
    gemm_bt<<<dim3(8, 16, 4), 256, 0, stream>>>(g2, 2048, 512, U_Wb, 512, 1024 * 512,
                                                zb, 0, 0, U_b, 1024, 1024, 512, 0, 1, 0);
    // Stage E: persistent scan — cooperative launch guarantees co-residency
    {
        const ushort_t* a0 = W_Wb; const float* a1 = W_b; const ushort_t* a2 = zb;
        const ushort_t* a3 = h0b;  const float* a4 = c0;  ushort_t* a5 = Hbt;
        unsigned int* a6 = flags;
        void* sargs[7] = {(void*)&a0, (void*)&a1, (void*)&a2, (void*)&a3,
                          (void*)&a4, (void*)&a5, (void*)&a6};
        hipLaunchCooperativeKernel((const void*)lstm_scan, dim3(SCAN_BLOCKS), dim3(256),
                                   sargs, 0, stream);
    }
    // Stage F: out = Hbt([t][b][h], aswap) (2048x1024) * C_W^T (10000x1024) + C_b (f32 out)
    gemm_bt<<<dim3(79, 16, 1), 256, 0, stream>>>(Hbt, 1024, 0, C_Wb, 1024, 0,
                                                 d_out, 10000, 0, C_b, 0,
                                                 10000, 1024, 1, 0, 1);
}

// Round 7
// 402.113 us; speedup vs baseline: 1.6330x; 1.0573x over previous
//
#include <hip/hip_runtime.h>
#include <hip/hip_bf16.h>

typedef __attribute__((ext_vector_type(8))) __bf16 bf16x8;
typedef __attribute__((ext_vector_type(4))) float f32x4;
typedef unsigned short ushort_t;

#define Bdim 64
#define Tdim 32
#define Edim 512
#define Fdim 512
#define Hdim 1024
#define Vdim 10000
#define SCAN_BLOCKS 64

__device__ __forceinline__ float bf2f(ushort_t u) {
    unsigned int x = ((unsigned int)u) << 16;
    union { unsigned int i; float f; } c; c.i = x; return c.f;
}
__device__ __forceinline__ ushort_t f2bf(float f) {
    __hip_bfloat16 h = __float2bfloat16(f);
    union { __hip_bfloat16 h; ushort_t u; } c; c.h = h; return c.u;
}

__device__ __forceinline__ void gload_lds16(const void* g, void* l) {
    __builtin_amdgcn_global_load_lds(
        (const __attribute__((address_space(1))) unsigned int*)g,
        (__attribute__((address_space(3))) unsigned int*)l, 16, 0, 0);
}

// write-through stores: visible device-wide once vmcnt-complete, no dirty local-L2 line
__device__ __forceinline__ void store_short_wt(ushort_t* p, ushort_t v) {
    asm volatile("global_store_short %0, %1, off sc0 sc1"
                 : : "v"(p), "v"((unsigned int)v) : "memory");
}
__device__ __forceinline__ void store_uint_wt(unsigned int* p, unsigned int v) {
    asm volatile("global_store_dword %0, %1, off sc0 sc1"
                 : : "v"(p), "v"(v) : "memory");
}

// ---------------- Stage 0: f32 -> bf16 mirror of weights + h0; zero flags ----------------
__global__ void cvt_all(const float* __restrict__ vw, const float* __restrict__ sw,
                        const float* __restrict__ uw, const float* __restrict__ ww,
                        const float* __restrict__ cw, const float* __restrict__ h0,
                        ushort_t* __restrict__ mir, unsigned int* __restrict__ flg) {
    if (blockIdx.x == 0) {   // zero flags[32][64] (8 KiB); visible after kernel-end release
        int4 zz = {0, 0, 0, 0};
        ((int4*)flg)[threadIdx.x * 2 + 0] = zz;
        ((int4*)flg)[threadIdx.x * 2 + 1] = zz;
    }
    long idx = ((long)blockIdx.x * blockDim.x + threadIdx.x) * 8;
    const float* src; long off;
    if      (idx <  1048576L) { src = vw; off = idx; }
    else if (idx <  2097152L) { src = sw; off = idx - 1048576L; }
    else if (idx <  4194304L) { src = uw; off = idx - 2097152L; }
    else if (idx <  8388608L) { src = ww; off = idx - 4194304L; }
    else if (idx < 18628608L) { src = cw; off = idx - 8388608L; }
    else if (idx < 18694144L) { src = h0; off = idx - 18628608L; }
    else return;
    float4 a = *(const float4*)(src + off);
    float4 b = *(const float4*)(src + off + 4);
    ushort_t o[8];
    o[0] = f2bf(a.x); o[1] = f2bf(a.y); o[2] = f2bf(a.z); o[3] = f2bf(a.w);
    o[4] = f2bf(b.x); o[5] = f2bf(b.y); o[6] = f2bf(b.z); o[7] = f2bf(b.w);
    *(int4*)(mir + idx) = *(const int4*)o;
}

// ---------------- Stage A: x = [img ; B_emb[captions[:, :-1]]], f32 -> bf16 ----------------
__global__ void build_x(const int* __restrict__ cap,
                        const float* __restrict__ img,
                        const float* __restrict__ emb,
                        ushort_t* __restrict__ X) {
    int idx = blockIdx.x * blockDim.x + threadIdx.x;
    int row = idx >> 6;
    int c8  = (idx & 63) << 3;
    int b = row >> 5, t = row & 31;
    const float* src = (t == 0) ? (img + (size_t)b * Edim)
                                : (emb + (size_t)cap[b * Tdim + (t - 1)] * Edim);
    float4 a  = *(const float4*)(src + c8);
    float4 bb = *(const float4*)(src + c8 + 4);
    ushort_t o[8];
    o[0] = f2bf(a.x);  o[1] = f2bf(a.y);  o[2] = f2bf(a.z);  o[3] = f2bf(a.w);
    o[4] = f2bf(bb.x); o[5] = f2bf(bb.y); o[6] = f2bf(bb.z); o[7] = f2bf(bb.w);
    *(int4*)(X + (size_t)row * Edim + c8) = *(const int4*)o;
}

// ---------------- Generic GEMM: C[m][n] = sum_k A[m][k]*Bt[n][k] + bias[n] ----------------
// T2 LDS XOR-swizzle; T1 XCD remap; zpack: [t][cg][g][hc][b] layout for lstm_scan.
// aswap=1: logical A-row (b*32+t) is stored at physical row (t*64+b)  (Hbt layout).
__launch_bounds__(256)
__global__ void gemm_bt(const ushort_t* __restrict__ A, long lda, long gsA,
                        const ushort_t* __restrict__ Bm, long ldb, long gsB,
                        void* __restrict__ Cv, long ldc, long gsC,
                        const float* __restrict__ bias, long gsBias,
                        int N, int K, int f32out, int zpack, int aswap) {
    __shared__ ushort_t As[128 * 64];
    __shared__ ushort_t Bs[128 * 64];
    int z = blockIdx.z;
    A += (size_t)z * gsA; Bm += (size_t)z * gsB; bias += (size_t)z * gsBias;

    // T1: XCD-aware remap (per-z slab; slab sizes here are all %8==0)
    int nx = gridDim.x, ny = gridDim.y;
    int lin = blockIdx.x + nx * blockIdx.y;
    int per_xcd = (nx * ny) >> 3;
    int l2 = (lin & 7) * per_xcd + (lin >> 3);
    int bx = l2 / ny, by = l2 % ny;

    int tid = threadIdx.x;
    int w = tid >> 6, l = tid & 63;
    int wm = (w >> 1) * 64, wn = (w & 1) * 64;
    int m0 = by * 128, n0 = bx * 128;

    int srow = tid >> 3;
    int scol = (tid & 7) << 3;

    int lane_r = l & 15;
    int lane_k = (l >> 4) << 3;

    f32x4 zero = {0.f, 0.f, 0.f, 0.f};
    f32x4 acc[4][4];
#pragma unroll
    for (int i = 0; i < 4; i++)
#pragma unroll
        for (int j = 0; j < 4; j++) acc[i][j] = zero;

    for (int k0 = 0; k0 < K; k0 += 64) {
#pragma unroll
        for (int j = 0; j < 4; j++) {
            int r = srow + j * 32;
            int pr = m0 + r;
            if (aswap) pr = ((pr & 31) << 6) + (pr >> 5);
            int sc = scol ^ ((r & 7) << 3);
            gload_lds16(A + (size_t)pr * lda + k0 + sc, &As[r * 64 + scol]);
        }
#pragma unroll
        for (int j = 0; j < 4; j++) {
            int r = srow + j * 32;
            int br = n0 + r; if (br > N - 1) br = N - 1;
            int sc = scol ^ ((r & 7) << 3);
            gload_lds16(Bm + (size_t)br * ldb + k0 + sc, &Bs[r * 64 + scol]);
        }
        __syncthreads();
#pragma unroll
        for (int kk = 0; kk < 64; kk += 32) {
            bf16x8 af[4], bfr[4];
#pragma unroll
            for (int i = 0; i < 4; i++) {
                int ar = wm + i * 16 + lane_r;
                af[i] = *(const bf16x8*)&As[ar * 64 + ((kk + lane_k) ^ ((ar & 7) << 3))];
            }
#pragma unroll
            for (int j = 0; j < 4; j++) {
                int br2 = wn + j * 16 + lane_r;
                bfr[j] = *(const bf16x8*)&Bs[br2 * 64 + ((kk + lane_k) ^ ((br2 & 7) << 3))];
            }
#pragma unroll
            for (int i = 0; i < 4; i++)
#pragma unroll
                for (int j = 0; j < 4; j++)
                    acc[i][j] = __builtin_amdgcn_mfma_f32_16x16x32_bf16(af[i], bfr[j], acc[i][j], 0, 0, 0);
        }
        __syncthreads();
    }

    int row_base = m0 + wm + ((l >> 4) << 2);
    int col_base = n0 + wn + lane_r;
#pragma unroll
    for (int j = 0; j < 4; j++) {
        int col = col_base + j * 16;
        if (col < N) {
            float bv = bias[col];
#pragma unroll
            for (int i = 0; i < 4; i++) {
#pragma unroll
                for (int r = 0; r < 4; r++) {
                    int row = row_base + i * 16 + r;
                    float v = acc[i][j][r] + bv;
                    if (zpack) {
                        int b = row >> 5, tt = row & 31;
                        size_t idx = (((size_t)(tt * 64 + (col >> 4)) * 4 + z) * 16
                                      + (col & 15)) * 64 + b;
                        ((ushort_t*)Cv)[idx] = f2bf(v);
                    } else if (f32out) {
                        ((float*)Cv)[(size_t)z * gsC + (size_t)row * ldc + col] = v;
                    } else {
                        ((ushort_t*)Cv)[(size_t)z * gsC + (size_t)row * ldc + col] = f2bf(v);
                    }
                }
            }
        }
    }
}

// ---------------- Stage E: persistent LSTM scan, flag dataflow + deep prefetch ----------------
// 64 blocks x 256 threads (cooperative). 1 block/CU (128 KiB LDS) -> 1 wave/SIMD ->
// zero TLP: the k-loop must hide remote-cache latency with ILP. 16-deep h-load ring
// keeps 16 loads in flight (~2 latency waves for 32 chunks).
__launch_bounds__(256, 1)
__global__ void lstm_scan(const ushort_t* __restrict__ Wm,   // bf16 [4*1024][1024]
                          const float* __restrict__ Wb,      // f32 [4][1024]
                          const ushort_t* __restrict__ zb,   // packed g3 [t][cg][g][hc][b]
                          const ushort_t* __restrict__ h0b,  // bf16 [64][1024]
                          const float* __restrict__ c0,      // f32 [64][1024]
                          ushort_t* __restrict__ Hbt,        // bf16 [t][64][1024]
                          unsigned int* __restrict__ flags) { // [32][64]
    __shared__ ushort_t Ws[64 * 1024];   // 128 KiB
    int cg = blockIdx.x;
    int tid = threadIdx.x;
    int w = tid >> 6, l = tid & 63;
    int lane_r = l & 15, lane_kb = (l >> 4) << 3;

    // ---- prologue: stage W slice into LDS with 16B XOR swizzle (reg-staged) ----
    for (int e = tid * 8; e < 65536; e += 2048) {
        int rowl = e >> 10, ke = e & 1023;
        int g = rowl >> 4, hc = rowl & 15;
        const ushort_t* src = Wm + ((size_t)(g * Hdim + cg * 16 + hc)) * Hdim + ke;
        int dstb = rowl * 2048 + ((ke * 2) ^ ((rowl & 7) << 4));
        *(int4*)((char*)Ws + dstb) = *(const int4*)src;
    }
    int hcol = cg * 16 + lane_r;
    float wbv[4];
#pragma unroll
    for (int g = 0; g < 4; g++) wbv[g] = Wb[g * Hdim + hcol];
    int rb0 = w * 16 + ((l >> 4) << 2);   // first of this thread's 4 batch rows
    float cst[4];
#pragma unroll
    for (int r = 0; r < 4; r++) cst[r] = c0[(size_t)(rb0 + r) * Hdim + hcol];
    __syncthreads();

    int arow = w * 16 + lane_r;
    int swz = (lane_r & 7) << 4;
    int rot = cg & 31;                    // staggered k-start spreads the all-to-all

    for (int t = 0; t < Tdim; t++) {
        // g3 loads for this step (independent of h) — issue before the poll
        ushort_t g3s[4][4];
        size_t zbase = ((size_t)t * 64 + cg) * 4096 + (size_t)lane_r * 64 + rb0;
#pragma unroll
        for (int g = 0; g < 4; g++)
            *(ushort4*)g3s[g] = *(const ushort4*)(zb + zbase + (size_t)g * 1024);

        // wait for ALL step-(t-1) producers: lane l watches flags[t-1][l]
        if (t > 0) {
            const unsigned int* fp = flags + (size_t)(t - 1) * 64 + l;
            unsigned int v;
            do {
                v = __hip_atomic_load(fp, __ATOMIC_RELAXED, __HIP_MEMORY_SCOPE_AGENT);
            } while (__ballot(v != 0) != 0xFFFFFFFFFFFFFFFFull);
        }

        const ushort_t* hp = t ? (Hbt + (size_t)(t - 1) * (Bdim * Hdim)) : h0b;
        const ushort_t* ap = hp + (size_t)arow * Hdim + lane_kb;

        f32x4 zero = {0.f, 0.f, 0.f, 0.f};
        f32x4 acc[4];
#pragma unroll
        for (int g = 0; g < 4; g++) acc[g] = zero;

        // 16-deep prefetch ring over 32 k-chunks (all indices compile-time)
        bf16x8 abuf[16];
#pragma unroll
        for (int p = 0; p < 16; p++)
            abuf[p] = *(const bf16x8*)(ap + (((p + rot) & 31) << 5));
#pragma unroll
        for (int d = 0; d < 32; d++) {
            bf16x8 a_cur = abuf[d & 15];
            if (d < 16)
                abuf[d & 15] = *(const bf16x8*)(ap + (((d + 16 + rot) & 31) << 5));
            int kc = ((d + rot) & 31) << 5;
#pragma unroll
            for (int g = 0; g < 4; g++) {
                bf16x8 b = *(const bf16x8*)((const char*)Ws
                              + ((g * 16 + lane_r) * 2048 + (((kc + lane_kb) * 2) ^ swz)));
                acc[g] = __builtin_amdgcn_mfma_f32_16x16x32_bf16(a_cur, b, acc[g], 0, 0, 0);
            }
        }

#pragma unroll
        for (int r = 0; r < 4; r++) {
            float zi = acc[0][r] + wbv[0] + bf2f(g3s[0][r]);
            float zf = acc[1][r] + wbv[1] + bf2f(g3s[1][r]);
            float zo = acc[2][r] + wbv[2] + bf2f(g3s[2][r]);
            float zc = acc[3][r] + wbv[3] + bf2f(g3s[3][r]);
            // fast gate math: v_exp + v_rcp approx (err ~1e-7 << bf16 rounding)
            float it = __builtin_amdgcn_rcpf(1.f + __expf(-zi));
            float ft = __builtin_amdgcn_rcpf(1.f + __expf(-zf));
            float ot = __builtin_amdgcn_rcpf(1.f + __expf(-zo));
            float e2 = __expf(-2.f * zc);
            float ct = (1.f - e2) * __builtin_amdgcn_rcpf(1.f + e2);
            float cn = ft * cst[r] + it * ct;
            cst[r] = cn;
            store_short_wt(Hbt + (size_t)t * (Bdim * Hdim) + (size_t)(rb0 + r) * Hdim + hcol,
                           f2bf(ot * cn));
        }

        // drain this wave's h stores, block-arrive, publish own flag (plain WT store)
        asm volatile("s_waitcnt vmcnt(0)" ::: "memory");
        __syncthreads();
        if (tid == 0) store_uint_wt(flags + (size_t)t * 64 + cg, 1u);
    }
}

extern "C" void kernel_launch(void* const* d_in, const int* in_sizes, int n_in,
                              void* d_out, int out_size, void* d_ws, size_t ws_size,
                              hipStream_t stream) {
    const int*   cap  = (const int*)d_in[0];
    const float* img  = (const float*)d_in[1];
    const float* Bemb = (const float*)d_in[2];
    const float* V_W  = (const float*)d_in[3];
    const float* V_b  = (const float*)d_in[4];
    const float* S_W  = (const float*)d_in[5];
    const float* S_b  = (const float*)d_in[6];
    const float* U_W  = (const float*)d_in[7];
    const float* U_b  = (const float*)d_in[8];
    const float* W_W  = (const float*)d_in[9];
    const float* W_b  = (const float*)d_in[10];
    const float* C_W  = (const float*)d_in[11];
    const float* C_b  = (const float*)d_in[12];
    const float* h0   = (const float*)d_in[13];
    const float* c0   = (const float*)d_in[14];

    char* ws = (char*)d_ws;
    ushort_t* mir = (ushort_t*)(ws);                       // 35.7 MiB bf16 mirror
    ushort_t* X   = (ushort_t*)(ws + (size_t)(36u << 20)); // 2 MiB
    ushort_t* g1  = (ushort_t*)(ws + (size_t)(38u << 20)); // 8 MiB
    ushort_t* g2  = (ushort_t*)(ws + (size_t)(46u << 20)); // 8 MiB
    ushort_t* Hbt = (ushort_t*)(ws + (size_t)(54u << 20)); // 4 MiB [t][b][h]
    unsigned int* flags = (unsigned int*)(ws + (size_t)(58u << 20)); // 8 KiB
    ushort_t* zb  = (ushort_t*)d_out;                      // 16 MiB scratch, dead before stage F

    const ushort_t* V_Wb = mir;
    const ushort_t* S_Wb = mir + 1048576L;
    const ushort_t* U_Wb = mir + 2097152L;
    const ushort_t* W_Wb = mir + 4194304L;
    const ushort_t* C_Wb = mir + 8388608L;
    const ushort_t* h0b  = mir + 18628608L;

    cvt_all<<<9128, 256, 0, stream>>>(V_W, S_W, U_W, W_W, C_W, h0, mir, flags);
    build_x<<<512, 256, 0, stream>>>(cap, img, Bemb, X);

    // Stage B: g1 = X (2048x512) * V_Wcat^T (2048x512) + V_b
    gemm_bt<<<dim3(16, 16, 1), 256, 0, stream>>>(X, 512, 0, V_Wb, 512, 0,
                                                 g1, 2048, 0, V_b, 0, 2048, 512, 0, 0, 0);
    // Stage C (per gate): g2[:, g] = g1[:, g] * S_W[g]^T + S_b[g]
    gemm_bt<<<dim3(4, 16, 4), 256, 0, stream>>>(g1, 2048, 512, S_Wb, 512, 512 * 512,
                                                g2, 2048, 512, S_b, 512, 512, 512, 0, 0, 0);
    // Stage D (per gate): zb(packed) = g2[:, g] * U_W[g]^T + U_b[g]
    gemm_bt<<<dim3(8, 16, 4), 256, 0, stream>>>(g2, 2048, 512, U_Wb, 512, 1024 * 512,
                                                zb, 0, 0, U_b, 1024, 1024, 512, 0, 1, 0);
    // Stage E: persistent scan — cooperative launch guarantees co-residency
    {
        const ushort_t* a0 = W_Wb; const float* a1 = W_b; const ushort_t* a2 = zb;
        const ushort_t* a3 = h0b;  const float* a4 = c0;  ushort_t* a5 = Hbt;
        unsigned int* a6 = flags;
        void* sargs[7] = {(void*)&a0, (void*)&a1, (void*)&a2, (void*)&a3,
                          (void*)&a4, (void*)&a5, (void*)&a6};
        hipLaunchCooperativeKernel((const void*)lstm_scan, dim3(SCAN_BLOCKS), dim3(256),
                                   sargs, 0, stream);
    }
    // Stage F: out = Hbt([t][b][h], aswap) (2048x1024) * C_W^T (10000x1024) + C_b (f32 out)
    gemm_bt<<<dim3(79, 16, 1), 256, 0, stream>>>(Hbt, 1024, 0, C_Wb, 1024, 0,
                                                 d_out, 10000, 0, C_b, 0,
                                                 10000, 1024, 1, 0, 1);
}

// Round 9
// 384.198 us; speedup vs baseline: 1.7091x; 1.0466x over previous
//
#include <hip/hip_runtime.h>
#include <hip/hip_bf16.h>

typedef __attribute__((ext_vector_type(8))) __bf16 bf16x8;
typedef __attribute__((ext_vector_type(4))) float f32x4;
typedef unsigned short ushort_t;

#define Bdim 64
#define Tdim 32
#define Edim 512
#define Fdim 512
#define Hdim 1024
#define Vdim 10000
#define SCAN_BLOCKS 64

__device__ __forceinline__ float bf2f(ushort_t u) {
    unsigned int x = ((unsigned int)u) << 16;
    union { unsigned int i; float f; } c; c.i = x; return c.f;
}
__device__ __forceinline__ ushort_t f2bf(float f) {
    __hip_bfloat16 h = __float2bfloat16(f);
    union { __hip_bfloat16 h; ushort_t u; } c; c.h = h; return c.u;
}

__device__ __forceinline__ void gload_lds16(const void* g, void* l) {
    __builtin_amdgcn_global_load_lds(
        (const __attribute__((address_space(1))) unsigned int*)g,
        (__attribute__((address_space(3))) unsigned int*)l, 16, 0, 0);
}

// write-through stores: visible device-wide once vmcnt-complete, no dirty local-L2 line
__device__ __forceinline__ void store_short_wt(ushort_t* p, ushort_t v) {
    asm volatile("global_store_short %0, %1, off sc0 sc1"
                 : : "v"(p), "v"((unsigned int)v) : "memory");
}
__device__ __forceinline__ void store_uint_wt(unsigned int* p, unsigned int v) {
    asm volatile("global_store_dword %0, %1, off sc0 sc1"
                 : : "v"(p), "v"(v) : "memory");
}

// ---------------- Stage 0: f32 -> bf16 mirror of weights + h0; zero flags ----------------
__global__ void cvt_all(const float* __restrict__ vw, const float* __restrict__ sw,
                        const float* __restrict__ uw, const float* __restrict__ ww,
                        const float* __restrict__ cw, const float* __restrict__ h0,
                        ushort_t* __restrict__ mir, unsigned int* __restrict__ flg) {
    if (blockIdx.x == 0) {   // zero flags[32][64] (8 KiB); visible after kernel-end release
        int4 zz = {0, 0, 0, 0};
        ((int4*)flg)[threadIdx.x * 2 + 0] = zz;
        ((int4*)flg)[threadIdx.x * 2 + 1] = zz;
    }
    long idx = ((long)blockIdx.x * blockDim.x + threadIdx.x) * 8;
    const float* src; long off;
    if      (idx <  1048576L) { src = vw; off = idx; }
    else if (idx <  2097152L) { src = sw; off = idx - 1048576L; }
    else if (idx <  4194304L) { src = uw; off = idx - 2097152L; }
    else if (idx <  8388608L) { src = ww; off = idx - 4194304L; }
    else if (idx < 18628608L) { src = cw; off = idx - 8388608L; }
    else if (idx < 18694144L) { src = h0; off = idx - 18628608L; }
    else return;
    float4 a = *(const float4*)(src + off);
    float4 b = *(const float4*)(src + off + 4);
    ushort_t o[8];
    o[0] = f2bf(a.x); o[1] = f2bf(a.y); o[2] = f2bf(a.z); o[3] = f2bf(a.w);
    o[4] = f2bf(b.x); o[5] = f2bf(b.y); o[6] = f2bf(b.z); o[7] = f2bf(b.w);
    *(int4*)(mir + idx) = *(const int4*)o;
}

// ---------------- Stage A: x = [img ; B_emb[captions[:, :-1]]], f32 -> bf16 ----------------
__global__ void build_x(const int* __restrict__ cap,
                        const float* __restrict__ img,
                        const float* __restrict__ emb,
                        ushort_t* __restrict__ X) {
    int idx = blockIdx.x * blockDim.x + threadIdx.x;
    int row = idx >> 6;
    int c8  = (idx & 63) << 3;
    int b = row >> 5, t = row & 31;
    const float* src = (t == 0) ? (img + (size_t)b * Edim)
                                : (emb + (size_t)cap[b * Tdim + (t - 1)] * Edim);
    float4 a  = *(const float4*)(src + c8);
    float4 bb = *(const float4*)(src + c8 + 4);
    ushort_t o[8];
    o[0] = f2bf(a.x);  o[1] = f2bf(a.y);  o[2] = f2bf(a.z);  o[3] = f2bf(a.w);
    o[4] = f2bf(bb.x); o[5] = f2bf(bb.y); o[6] = f2bf(bb.z); o[7] = f2bf(bb.w);
    *(int4*)(X + (size_t)row * Edim + c8) = *(const int4*)o;
}

// ---------------- Generic GEMM: C[m][n] = sum_k A[m][k]*Bt[n][k] + bias[n] ----------------
// T2 LDS XOR-swizzle; T1 XCD remap; zpack: [t][cg][g][hc][b] layout for lstm_scan.
// aswap=1: logical A-row (b*32+t) is stored at physical row (t*64+b)  (Hbt layout).
__launch_bounds__(256)
__global__ void gemm_bt(const ushort_t* __restrict__ A, long lda, long gsA,
                        const ushort_t* __restrict__ Bm, long ldb, long gsB,
                        void* __restrict__ Cv, long ldc, long gsC,
                        const float* __restrict__ bias, long gsBias,
                        int N, int K, int f32out, int zpack, int aswap) {
    __shared__ ushort_t As[128 * 64];
    __shared__ ushort_t Bs[128 * 64];
    int z = blockIdx.z;
    A += (size_t)z * gsA; Bm += (size_t)z * gsB; bias += (size_t)z * gsBias;

    // T1: XCD-aware remap (per-z slab; slab sizes here are all %8==0)
    int nx = gridDim.x, ny = gridDim.y;
    int lin = blockIdx.x + nx * blockIdx.y;
    int per_xcd = (nx * ny) >> 3;
    int l2 = (lin & 7) * per_xcd + (lin >> 3);
    int bx = l2 / ny, by = l2 % ny;

    int tid = threadIdx.x;
    int w = tid >> 6, l = tid & 63;
    int wm = (w >> 1) * 64, wn = (w & 1) * 64;
    int m0 = by * 128, n0 = bx * 128;

    int srow = tid >> 3;
    int scol = (tid & 7) << 3;

    int lane_r = l & 15;
    int lane_k = (l >> 4) << 3;

    f32x4 zero = {0.f, 0.f, 0.f, 0.f};
    f32x4 acc[4][4];
#pragma unroll
    for (int i = 0; i < 4; i++)
#pragma unroll
        for (int j = 0; j < 4; j++) acc[i][j] = zero;

    for (int k0 = 0; k0 < K; k0 += 64) {
#pragma unroll
        for (int j = 0; j < 4; j++) {
            int r = srow + j * 32;
            int pr = m0 + r;
            if (aswap) pr = ((pr & 31) << 6) + (pr >> 5);
            int sc = scol ^ ((r & 7) << 3);
            gload_lds16(A + (size_t)pr * lda + k0 + sc, &As[r * 64 + scol]);
        }
#pragma unroll
        for (int j = 0; j < 4; j++) {
            int r = srow + j * 32;
            int br = n0 + r; if (br > N - 1) br = N - 1;
            int sc = scol ^ ((r & 7) << 3);
            gload_lds16(Bm + (size_t)br * ldb + k0 + sc, &Bs[r * 64 + scol]);
        }
        __syncthreads();
#pragma unroll
        for (int kk = 0; kk < 64; kk += 32) {
            bf16x8 af[4], bfr[4];
#pragma unroll
            for (int i = 0; i < 4; i++) {
                int ar = wm + i * 16 + lane_r;
                af[i] = *(const bf16x8*)&As[ar * 64 + ((kk + lane_k) ^ ((ar & 7) << 3))];
            }
#pragma unroll
            for (int j = 0; j < 4; j++) {
                int br2 = wn + j * 16 + lane_r;
                bfr[j] = *(const bf16x8*)&Bs[br2 * 64 + ((kk + lane_k) ^ ((br2 & 7) << 3))];
            }
#pragma unroll
            for (int i = 0; i < 4; i++)
#pragma unroll
                for (int j = 0; j < 4; j++)
                    acc[i][j] = __builtin_amdgcn_mfma_f32_16x16x32_bf16(af[i], bfr[j], acc[i][j], 0, 0, 0);
        }
        __syncthreads();
    }

    int row_base = m0 + wm + ((l >> 4) << 2);
    int col_base = n0 + wn + lane_r;
#pragma unroll
    for (int j = 0; j < 4; j++) {
        int col = col_base + j * 16;
        if (col < N) {
            float bv = bias[col];
#pragma unroll
            for (int i = 0; i < 4; i++) {
#pragma unroll
                for (int r = 0; r < 4; r++) {
                    int row = row_base + i * 16 + r;
                    float v = acc[i][j][r] + bv;
                    if (zpack) {
                        int b = row >> 5, tt = row & 31;
                        size_t idx = (((size_t)(tt * 64 + (col >> 4)) * 4 + z) * 16
                                      + (col & 15)) * 64 + b;
                        ((ushort_t*)Cv)[idx] = f2bf(v);
                    } else if (f32out) {
                        ((float*)Cv)[(size_t)z * gsC + (size_t)row * ldc + col] = v;
                    } else {
                        ((ushort_t*)Cv)[(size_t)z * gsC + (size_t)row * ldc + col] = f2bf(v);
                    }
                }
            }
        }
    }
}

// hand-issued 16B load with literal offset into ring slot i (compiler cannot serialize)
#define GLD(i, o) asm volatile("global_load_dwordx4 %0, %1, off offset:" o \
                               : "=v"(ab[i]) : "v"(apx))
// One k-chunk: ds_reads BEFORE the counted wait (overlap LDS latency with vmcnt wait);
// sched_barrier(0) is the ONLY verified fence vs MFMA hoisting past inline-asm waitcnt
// (rule #18 — round 8's mask 0x3F7 let MFMA hoist -> garbage). ISSUE refills the ring.
#define CHUNK(d, n, ISSUE)                                                                   \
    do {                                                                                     \
        const int kc2 = ((d) * 32 + lane_kb) * 2;                                            \
        bf16x8 b0 = *(const bf16x8*)((const char*)Ws + ((     lane_r) * 2048 + (kc2 ^ swz)));\
        bf16x8 b1 = *(const bf16x8*)((const char*)Ws + ((16 + lane_r) * 2048 + (kc2 ^ swz)));\
        bf16x8 b2 = *(const bf16x8*)((const char*)Ws + ((32 + lane_r) * 2048 + (kc2 ^ swz)));\
        bf16x8 b3 = *(const bf16x8*)((const char*)Ws + ((48 + lane_r) * 2048 + (kc2 ^ swz)));\
        asm volatile("s_waitcnt vmcnt(" n ")");                                              \
        __builtin_amdgcn_sched_barrier(0);                                                   \
        bf16x8 av = __builtin_bit_cast(bf16x8, ab[(d) & 15]);                                \
        acc[0] = __builtin_amdgcn_mfma_f32_16x16x32_bf16(av, b0, acc[0], 0, 0, 0);           \
        acc[1] = __builtin_amdgcn_mfma_f32_16x16x32_bf16(av, b1, acc[1], 0, 0, 0);           \
        acc[2] = __builtin_amdgcn_mfma_f32_16x16x32_bf16(av, b2, acc[2], 0, 0, 0);           \
        acc[3] = __builtin_amdgcn_mfma_f32_16x16x32_bf16(av, b3, acc[3], 0, 0, 0);           \
        ISSUE;                                                                               \
    } while (0)

// ---------------- Stage E: persistent LSTM scan, flag dataflow + 16-deep asm ring ----------
// 64 blocks x 256 threads (cooperative). 1 block/CU -> 1 wave/SIMD -> zero TLP: h-chunk
// loads hand-issued (16 in flight, ring-refilled), consumed with counted vmcnt.
// Ring math: chunks 0..16 wait vmcnt(15) (issued grows with d), 17..31 wait 14..0.
__launch_bounds__(256, 1)
__global__ void lstm_scan(const ushort_t* __restrict__ Wm,   // bf16 [4*1024][1024]
                          const float* __restrict__ Wb,      // f32 [4][1024]
                          const ushort_t* __restrict__ zb,   // packed g3 [t][cg][g][hc][b]
                          const ushort_t* __restrict__ h0b,  // bf16 [64][1024]
                          const float* __restrict__ c0,      // f32 [64][1024]
                          ushort_t* __restrict__ Hbt,        // bf16 [t][64][1024]
                          unsigned int* __restrict__ flags) { // [32][64]
    __shared__ ushort_t Ws[64 * 1024];   // 128 KiB
    int cg = blockIdx.x;
    int tid = threadIdx.x;
    int w = tid >> 6, l = tid & 63;
    int lane_r = l & 15, lane_kb = (l >> 4) << 3;

    // ---- prologue: stage W slice into LDS with 16B XOR swizzle (reg-staged) ----
    for (int e = tid * 8; e < 65536; e += 2048) {
        int rowl = e >> 10, ke = e & 1023;
        int g = rowl >> 4, hc = rowl & 15;
        const ushort_t* src = Wm + ((size_t)(g * Hdim + cg * 16 + hc)) * Hdim + ke;
        int dstb = rowl * 2048 + ((ke * 2) ^ ((rowl & 7) << 4));
        *(int4*)((char*)Ws + dstb) = *(const int4*)src;
    }
    int hcol = cg * 16 + lane_r;
    float wbv[4];
#pragma unroll
    for (int g = 0; g < 4; g++) wbv[g] = Wb[g * Hdim + hcol];
    int rb0 = w * 16 + ((l >> 4) << 2);   // first of this thread's 4 batch rows
    float cst[4];
#pragma unroll
    for (int r = 0; r < 4; r++) cst[r] = c0[(size_t)(rb0 + r) * Hdim + hcol];
    __syncthreads();

    int arow = w * 16 + lane_r;
    int swz = (lane_r & 7) << 4;

    for (int t = 0; t < Tdim; t++) {
        // g3 loads for this step (independent of h) — issue before the poll
        ushort_t g3s[4][4];
        size_t zbase = ((size_t)t * 64 + cg) * 4096 + (size_t)lane_r * 64 + rb0;
#pragma unroll
        for (int g = 0; g < 4; g++)
            *(ushort4*)g3s[g] = *(const ushort4*)(zb + zbase + (size_t)g * 1024);

        // wait for ALL step-(t-1) producers: lane l watches flags[t-1][l]
        if (t > 0) {
            const unsigned int* fp = flags + (size_t)(t - 1) * 64 + l;
            unsigned int v;
            do {
                v = __hip_atomic_load(fp, __ATOMIC_RELAXED, __HIP_MEMORY_SCOPE_AGENT);
            } while (__ballot(v != 0) != 0xFFFFFFFFFFFFFFFFull);
        }
        __builtin_amdgcn_sched_barrier(0);   // nothing crosses the poll

        const ushort_t* hp = t ? (Hbt + (size_t)(t - 1) * (Bdim * Hdim)) : h0b;
        const ushort_t* apx = hp + (size_t)arow * Hdim + lane_kb;

        // prime the 16-deep ring (chunks 0..15; 64B apart)
        int4 ab[16];
        GLD(0, "0");    GLD(1, "64");   GLD(2, "128");  GLD(3, "192");
        GLD(4, "256");  GLD(5, "320");  GLD(6, "384");  GLD(7, "448");
        GLD(8, "512");  GLD(9, "576");  GLD(10, "640"); GLD(11, "704");
        GLD(12, "768"); GLD(13, "832"); GLD(14, "896"); GLD(15, "960");

        f32x4 zero = {0.f, 0.f, 0.f, 0.f};
        f32x4 acc[4];
#pragma unroll
        for (int g = 0; g < 4; g++) acc[g] = zero;

        CHUNK(0, "15", GLD(0, "1024"));  CHUNK(1, "15", GLD(1, "1088"));
        CHUNK(2, "15", GLD(2, "1152"));  CHUNK(3, "15", GLD(3, "1216"));
        CHUNK(4, "15", GLD(4, "1280"));  CHUNK(5, "15", GLD(5, "1344"));
        CHUNK(6, "15", GLD(6, "1408"));  CHUNK(7, "15", GLD(7, "1472"));
        CHUNK(8, "15", GLD(8, "1536"));  CHUNK(9, "15", GLD(9, "1600"));
        CHUNK(10, "15", GLD(10, "1664")); CHUNK(11, "15", GLD(11, "1728"));
        CHUNK(12, "15", GLD(12, "1792")); CHUNK(13, "15", GLD(13, "1856"));
        CHUNK(14, "15", GLD(14, "1920")); CHUNK(15, "15", GLD(15, "1984"));
        CHUNK(16, "15", (void)0); CHUNK(17, "14", (void)0);
        CHUNK(18, "13", (void)0); CHUNK(19, "12", (void)0);
        CHUNK(20, "11", (void)0); CHUNK(21, "10", (void)0);
        CHUNK(22, "9", (void)0);  CHUNK(23, "8", (void)0);
        CHUNK(24, "7", (void)0);  CHUNK(25, "6", (void)0);
        CHUNK(26, "5", (void)0);  CHUNK(27, "4", (void)0);
        CHUNK(28, "3", (void)0);  CHUNK(29, "2", (void)0);
        CHUNK(30, "1", (void)0);  CHUNK(31, "0", (void)0);

#pragma unroll
        for (int r = 0; r < 4; r++) {
            float zi = acc[0][r] + wbv[0] + bf2f(g3s[0][r]);
            float zf = acc[1][r] + wbv[1] + bf2f(g3s[1][r]);
            float zo = acc[2][r] + wbv[2] + bf2f(g3s[2][r]);
            float zc = acc[3][r] + wbv[3] + bf2f(g3s[3][r]);
            // fast gate math: v_exp + v_rcp approx (err ~1e-7 << bf16 rounding)
            float it = __builtin_amdgcn_rcpf(1.f + __expf(-zi));
            float ft = __builtin_amdgcn_rcpf(1.f + __expf(-zf));
            float ot = __builtin_amdgcn_rcpf(1.f + __expf(-zo));
            float e2 = __expf(-2.f * zc);
            float ct = (1.f - e2) * __builtin_amdgcn_rcpf(1.f + e2);
            float cn = ft * cst[r] + it * ct;
            cst[r] = cn;
            store_short_wt(Hbt + (size_t)t * (Bdim * Hdim) + (size_t)(rb0 + r) * Hdim + hcol,
                           f2bf(ot * cn));
        }

        // drain this wave's h stores, block-arrive, publish own flag (plain WT store)
        asm volatile("s_waitcnt vmcnt(0)" ::: "memory");
        __syncthreads();
        if (tid == 0) store_uint_wt(flags + (size_t)t * 64 + cg, 1u);
    }
}

extern "C" void kernel_launch(void* const* d_in, const int* in_sizes, int n_in,
                              void* d_out, int out_size, void* d_ws, size_t ws_size,
                              hipStream_t stream) {
    const int*   cap  = (const int*)d_in[0];
    const float* img  = (const float*)d_in[1];
    const float* Bemb = (const float*)d_in[2];
    const float* V_W  = (const float*)d_in[3];
    const float* V_b  = (const float*)d_in[4];
    const float* S_W  = (const float*)d_in[5];
    const float* S_b  = (const float*)d_in[6];
    const float* U_W  = (const float*)d_in[7];
    const float* U_b  = (const float*)d_in[8];
    const float* W_W  = (const float*)d_in[9];
    const float* W_b  = (const float*)d_in[10];
    const float* C_W  = (const float*)d_in[11];
    const float* C_b  = (const float*)d_in[12];
    const float* h0   = (const float*)d_in[13];
    const float* c0   = (const float*)d_in[14];

    char* ws = (char*)d_ws;
    ushort_t* mir = (ushort_t*)(ws);                       // 35.7 MiB bf16 mirror
    ushort_t* X   = (ushort_t*)(ws + (size_t)(36u << 20)); // 2 MiB
    ushort_t* g1  = (ushort_t*)(ws + (size_t)(38u << 20)); // 8 MiB
    ushort_t* g2  = (ushort_t*)(ws + (size_t)(46u << 20)); // 8 MiB
    ushort_t* Hbt = (ushort_t*)(ws + (size_t)(54u << 20)); // 4 MiB [t][b][h]
    unsigned int* flags = (unsigned int*)(ws + (size_t)(58u << 20)); // 8 KiB
    ushort_t* zb  = (ushort_t*)d_out;                      // 16 MiB scratch, dead before stage F

    const ushort_t* V_Wb = mir;
    const ushort_t* S_Wb = mir + 1048576L;
    const ushort_t* U_Wb = mir + 2097152L;
    const ushort_t* W_Wb = mir + 4194304L;
    const ushort_t* C_Wb = mir + 8388608L;
    const ushort_t* h0b  = mir + 18628608L;

    cvt_all<<<9128, 256, 0, stream>>>(V_W, S_W, U_W, W_W, C_W, h0, mir, flags);
    build_x<<<512, 256, 0, stream>>>(cap, img, Bemb, X);

    // Stage B: g1 = X (2048x512) * V_Wcat^T (2048x512) + V_b
    gemm_bt<<<dim3(16, 16, 1), 256, 0, stream>>>(X, 512, 0, V_Wb, 512, 0,
                                                 g1, 2048, 0, V_b, 0, 2048, 512, 0, 0, 0);
    // Stage C (per gate): g2[:, g] = g1[:, g] * S_W[g]^T + S_b[g]
    gemm_bt<<<dim3(4, 16, 4), 256, 0, stream>>>(g1, 2048, 512, S_Wb, 512, 512 * 512,
                                                g2, 2048, 512, S_b, 512, 512, 512, 0, 0, 0);
    // Stage D (per gate): zb(packed) = g2[:, g] * U_W[g]^T + U_b[g]
    gemm_bt<<<dim3(8, 16, 4), 256, 0, stream>>>(g2, 2048, 512, U_Wb, 512, 1024 * 512,
                                                zb, 0, 0, U_b, 1024, 1024, 512, 0, 1, 0);
    // Stage E: persistent scan — cooperative launch guarantees co-residency
    {
        const ushort_t* a0 = W_Wb; const float* a1 = W_b; const ushort_t* a2 = zb;
        const ushort_t* a3 = h0b;  const float* a4 = c0;  ushort_t* a5 = Hbt;
        unsigned int* a6 = flags;
        void* sargs[7] = {(void*)&a0, (void*)&a1, (void*)&a2, (void*)&a3,
                          (void*)&a4, (void*)&a5, (void*)&a6};
        hipLaunchCooperativeKernel((const void*)lstm_scan, dim3(SCAN_BLOCKS), dim3(256),
                                   sargs, 0, stream);
    }
    // Stage F: out = Hbt([t][b][h], aswap) (2048x1024) * C_W^T (10000x1024) + C_b (f32 out)
    gemm_bt<<<dim3(79, 16, 1), 256, 0, stream>>>(Hbt, 1024, 0, C_Wb, 1024, 0,
                                                 d_out, 10000, 0, C_b, 0,
                                                 10000, 1024, 1, 0, 1);
}